// Round 13
// baseline (216.138 us; speedup 1.0000x reference)
//
#include <hip/hip_runtime.h>
#include <math.h>

// ---------------------------------------------------------------------------
// MambaAnglePredictor — Round 13 (R12 +):
//   phase3: C/B GM-operands direct-loaded from global (fragment-order rows),
//     sC dropped, 1 barrier (was 3), LDS 51.2->32.8 KB; Sp pre-split loads
//   phase2p: emits Sp as bf16 hi/lo (bit-identical, kills phase3 split VALU)
//   prep folds norm_w into Weff2; gate writes g*rms
// ---------------------------------------------------------------------------

#define BDIM 4
#define LDIM 4096
#define BL (BDIM*LDIM)      // 16384 tokens
#define QC 64
#define NC (LDIM/QC)        // 64
#define BH (BDIM*NH)        // 32
#define NH 8

// workspace offsets (floats)
#define OFF_W    0u          // Weff 4x904 @0, beff @4096, Weff2 @8192
#define OFF_Z    3145728u    // yn bf16
#define OFF_T    9437184u    // T [p][n] per chunk (fp32)
#define OFF_XS   17825792u   // xs_h | xs_l
#define OFF_BM   24117248u   // Bm_h | Bm_l
#define OFF_CM   25165824u   // Cm_h | Cm_l
#define OFF_DT   26214400u   // 32*4096 fp32
#define OFF_LAC  26345472u   // 2048*64 fp32
#define OFF_SP   26476544u   // Sp_h | Sp_l (bf16 hi/lo, [p][n] per chunk)
#define OFF_Y    32768000u   // y bf16
#define OFF_MACC 39059456u   // 4*32

typedef unsigned short ushort_t;
typedef __attribute__((ext_vector_type(8))) short bf16x8;
typedef __attribute__((ext_vector_type(4))) float f32x4;

__device__ __forceinline__ float sigmoidf_(float x){ return 1.0f/(1.0f+__expf(-x)); }
__device__ __forceinline__ ushort_t f2bf(float x){
  unsigned int u = __float_as_uint(x);
  u += 0x7fffu + ((u>>16)&1u);
  return (ushort_t)(u>>16);
}
__device__ __forceinline__ float bf2f(ushort_t h){
  return __uint_as_float(((unsigned int)h)<<16);
}

// ----- prep (merged): Weff, beff, Weff2 (nw-folded), macc zero -----
__global__ void k_prep(const float* __restrict__ Wfc, const float* __restrict__ bfc,
                       const float* __restrict__ W_in, const float* __restrict__ W_out,
                       const float* __restrict__ W1, const float* __restrict__ norm_w,
                       float* __restrict__ Weff, float* __restrict__ beff,
                       float* __restrict__ Weff2, float* __restrict__ macc){
  int blk = blockIdx.x, tid = threadIdx.x;
  if (blk < 4){
    int n = blk*256 + tid;
    if (n >= 904) return;
    float a0=0.f,a1=0.f,a2=0.f,a3=0.f,ab=0.f;
    for (int d=0; d<192; d++){
      float w = W_in[(size_t)d*904 + n];
      a0 = fmaf(Wfc[d], w, a0);
      a1 = fmaf(Wfc[192+d], w, a1);
      a2 = fmaf(Wfc[384+d], w, a2);
      a3 = fmaf(Wfc[576+d], w, a3);
      ab = fmaf(bfc[d], w, ab);
    }
    Weff[n] = a0; Weff[904+n] = a1; Weff[1808+n] = a2; Weff[2712+n] = a3;
    beff[n] = ab;
  } else {
    if (blk == 4 && tid < 128) macc[tid] = 0.f;
    int g = (blk-4)*256 + tid;
    int i = g>>5, j = g&31;
    float a = 0.f;
    for (int d=0; d<192; d++) a = fmaf(W_out[(size_t)i*192+d], W1[d*32+j], a);
    Weff2[g] = a * norm_w[i];
  }
}

// ----- ipc: fused in_proj+conv+silu+dt; outputs pre-split bf16 hi/lo -----
__global__ __launch_bounds__(256) void k_ipc(
    const float* __restrict__ x, const float* __restrict__ Weff,
    const float* __restrict__ beff, const float* __restrict__ conv_w,
    const float* __restrict__ conv_b, const float* __restrict__ dt_bias,
    ushort_t* __restrict__ xs_h, ushort_t* __restrict__ xs_l,
    ushort_t* __restrict__ Bm_h, ushort_t* __restrict__ Bm_l,
    ushort_t* __restrict__ Cm_h, ushort_t* __restrict__ Cm_l,
    float* __restrict__ dtb){
  __shared__ float sx[4][4];
  int bl = blockIdx.x, tid = threadIdx.x;
  int l = bl & 4095, b = bl >> 12;
  if (tid < 16){
    int k = tid>>2, r = tid&3;
    int ll = l-3+k;
    sx[k][r] = (ll>=0) ? x[(size_t)(b*4096+ll)*4 + r] : 0.f;
  }
  __syncthreads();
  if (tid < 8){
    float raw = beff[896+tid];
    #pragma unroll
    for (int r=0;r<4;r++) raw = fmaf(sx[3][r], Weff[r*904+896+tid], raw);
    float xx = raw + dt_bias[tid];
    float dtv = (xx > 20.f) ? xx : log1pf(__expf(xx));
    dtb[(size_t)(b*8+tid)*4096 + l] = dtv;
  }
  #pragma unroll
  for (int half=0; half<2; half++){
    int c = tid + half*256;
    float w0 = Weff[384+c];
    float w1 = Weff[904+384+c];
    float w2 = Weff[1808+384+c];
    float w3 = Weff[2712+384+c];
    float bb = beff[384+c];
    float acc = conv_b[c];
    #pragma unroll
    for (int k=0;k<4;k++){
      int ll = l-3+k;
      float xv = bb;
      xv = fmaf(sx[k][0], w0, xv);
      xv = fmaf(sx[k][1], w1, xv);
      xv = fmaf(sx[k][2], w2, xv);
      xv = fmaf(sx[k][3], w3, xv);
      if (ll < 0) xv = 0.f;
      acc = fmaf(conv_w[k*512+c], xv, acc);
    }
    float v = acc * sigmoidf_(acc);
    ushort_t hi = f2bf(v);
    ushort_t lo = f2bf(v - bf2f(hi));
    if (c < 384){
      int hh = c / 48, p = c - hh*48;
      size_t idx = (size_t)((b*8+hh)*4096 + l)*48 + p;
      xs_h[idx] = hi; xs_l[idx] = lo;
    } else if (c < 448){
      size_t idx = (size_t)bl*64 + (c-384);
      Bm_h[idx] = hi; Bm_l[idx] = lo;
    } else {
      size_t idx = (size_t)bl*64 + (c-448);
      Cm_h[idx] = hi; Cm_l[idx] = lo;
    }
  }
}

// ----- phase1 (MFMA): T^T[p][n] = X^T · Bw per chunk; writes lac -----
__global__ __launch_bounds__(256, 3) void k_phase1(
    const float* __restrict__ dtbuf,
    const ushort_t* __restrict__ Bm_h, const ushort_t* __restrict__ Bm_l,
    const ushort_t* __restrict__ xs_h, const ushort_t* __restrict__ xs_l,
    const float* __restrict__ A_log,
    float* __restrict__ T, float* __restrict__ lac){
  __shared__ __align__(16) ushort_t sBh[64*72], sBl[64*72];   // Bw^T [n][s]
  __shared__ __align__(16) ushort_t sXh[48*72], sXl[48*72];   // X^T [p][s]
  __shared__ float sdt[64], sla[64], sw[64];
  int tid = threadIdx.x, blk = blockIdx.x;
  int bh = blk >> 6, k = blk & 63;
  int b = bh >> 3, hh = bh & 7;
  int t0 = k*64;
  int w = tid>>6, lane = tid&63, l15 = lane&15, quad = lane>>4;

  if (tid < 64) sdt[tid] = dtbuf[(size_t)bh*4096 + t0 + tid];
  __syncthreads();
  if (tid == 0){
    float eA = __expf(A_log[hh]);
    float cum = 0.f;
    for (int i=0;i<64;i++){ cum -= sdt[i]*eA; sla[i] = cum; }
  }
  __syncthreads();
  if (tid < 64){
    sw[tid] = __expf(sla[63]-sla[tid])*sdt[tid];
    lac[(size_t)blk*64 + tid] = sla[tid];
  }
  __syncthreads();
  // ---- stage Bw^T [n][s]: reconstruct, scale by sw, re-split ----
  {
    int s2 = (tid&31)*2, ng = (tid>>5)*8;
    size_t base0 = (size_t)(b*4096+t0+s2)*64 + ng;
    ushort_t h0a[8], l0a[8], h1a[8], l1a[8];
    *(uint4*)h0a = *(const uint4*)(Bm_h + base0);
    *(uint4*)l0a = *(const uint4*)(Bm_l + base0);
    *(uint4*)h1a = *(const uint4*)(Bm_h + base0 + 64);
    *(uint4*)l1a = *(const uint4*)(Bm_l + base0 + 64);
    float w0 = sw[s2], w1 = sw[s2+1];
    #pragma unroll
    for (int c=0;c<8;c++){
      float f0 = (bf2f(h0a[c]) + bf2f(l0a[c])) * w0;
      float f1 = (bf2f(h1a[c]) + bf2f(l1a[c])) * w1;
      ushort_t h0 = f2bf(f0), h1 = f2bf(f1);
      ushort_t lo0 = f2bf(f0-bf2f(h0)), lo1 = f2bf(f1-bf2f(h1));
      int o = (ng+c)*72 + s2;
      *(unsigned int*)&sBh[o] = (unsigned int)h0 | ((unsigned int)h1<<16);
      *(unsigned int*)&sBl[o] = (unsigned int)lo0 | ((unsigned int)lo1<<16);
    }
  }
  // ---- stage X^T [p][s]: pure copy + pack (pre-split) ----
  {
    int s2 = (tid>>3)*2, p0 = (tid&7)*6;
    const ushort_t* xh0 = xs_h + (size_t)(bh*4096+t0+s2)*48 + p0;
    const ushort_t* xl0 = xs_l + (size_t)(bh*4096+t0+s2)*48 + p0;
    #pragma unroll
    for (int c=0;c<6;c++){
      unsigned int hv = (unsigned int)xh0[c] | ((unsigned int)xh0[48+c]<<16);
      unsigned int lv = (unsigned int)xl0[c] | ((unsigned int)xl0[48+c]<<16);
      int o = (p0+c)*72 + s2;
      *(unsigned int*)&sXh[o] = hv;
      *(unsigned int*)&sXl[o] = lv;
    }
  }
  __syncthreads();
  f32x4 acc[3];
  #pragma unroll
  for (int t=0;t<3;t++) acc[t] = (f32x4)(0.f);
  #pragma unroll
  for (int ks=0;ks<2;ks++){
    int bo = (w*16+l15)*72 + ks*32 + quad*8;
    bf16x8 bbh = *(bf16x8*)&sBh[bo];
    bf16x8 bbl = *(bf16x8*)&sBl[bo];
    #pragma unroll
    for (int pt=0;pt<3;pt++){
      int xo = (pt*16+l15)*72 + ks*32 + quad*8;
      bf16x8 xah = *(bf16x8*)&sXh[xo];
      bf16x8 xal = *(bf16x8*)&sXl[xo];
      acc[pt] = __builtin_amdgcn_mfma_f32_16x16x32_bf16(xah, bbh, acc[pt], 0,0,0);
      acc[pt] = __builtin_amdgcn_mfma_f32_16x16x32_bf16(xah, bbl, acc[pt], 0,0,0);
      acc[pt] = __builtin_amdgcn_mfma_f32_16x16x32_bf16(xal, bbh, acc[pt], 0,0,0);
    }
  }
  {
    float* dst = T + (size_t)blk*3072;
    #pragma unroll
    for (int pt=0;pt<3;pt++)
      #pragma unroll
      for (int r=0;r<4;r++)
        dst[(pt*16+quad*4+r)*64 + w*16 + l15] = acc[pt][r];
  }
}

// ----- phase2p: Sp[k] = sum_{j<k} W[k][j] T[j]; emits bf16 hi/lo -----
__global__ __launch_bounds__(256) void k_phase2p(
    const float* __restrict__ T, const float* __restrict__ lac,
    ushort_t* __restrict__ Sp_h, ushort_t* __restrict__ Sp_l){
  __shared__ __align__(16) float sT[64*64];
  __shared__ __align__(16) float sW[64][68];
  __shared__ float sc[64];
  int tid = threadIdx.x;
  int bh = blockIdx.x, es = blockIdx.y;
  #pragma unroll
  for (int r=0;r<4;r++){
    int idx = tid + r*256;
    int row = idx>>4, c4 = (idx&15)*4;
    *(float4*)&sT[row*64 + c4] = *(const float4*)(T + (size_t)(bh*64+row)*3072 + es*64 + c4);
  }
  if (tid < 64) sc[tid] = __expf(lac[(size_t)(bh*64+tid)*64 + 63]);
  __syncthreads();
  if (tid < 64){
    int k = tid;
    float w = 1.f;
    for (int j=63; j>=0; --j){
      bool a = (j < k);
      sW[j][k] = a ? w : 0.f;
      if (a) w *= sc[j];
    }
  }
  __syncthreads();
  int k0 = (tid>>4)*4, e0 = (tid&15)*4;
  float acc[4][4];
  #pragma unroll
  for (int i=0;i<4;i++)
    #pragma unroll
    for (int j=0;j<4;j++) acc[i][j]=0.f;
  int jmax = k0+2; if (jmax > 62) jmax = 62;
  for (int j=0; j<=jmax; ++j){
    float wv[4], tv[4];
    *(float4*)wv = *(float4*)&sW[j][k0];
    *(float4*)tv = *(float4*)&sT[j*64 + e0];
    #pragma unroll
    for (int i=0;i<4;i++)
      #pragma unroll
      for (int e=0;e<4;e++) acc[i][e] = fmaf(wv[i], tv[e], acc[i][e]);
  }
  #pragma unroll
  for (int i=0;i<4;i++){
    ushort4 h4, l4;
    ushort_t* hp = (ushort_t*)&h4;
    ushort_t* lp = (ushort_t*)&l4;
    #pragma unroll
    for (int e=0;e<4;e++){
      ushort_t hi = f2bf(acc[i][e]);
      hp[e] = hi;
      lp[e] = f2bf(acc[i][e] - bf2f(hi));
    }
    size_t o = (size_t)(bh*64+k0+i)*3072 + es*64 + e0;
    *(ushort4*)(Sp_h + o) = h4;
    *(ushort4*)(Sp_l + o) = l4;
  }
}

// ----- phase3 (MFMA): GM = mask(C·B^T)*decay; O = X^T·GM^T + e^la·(Sp^T·C^T) + Dx
// C/B GM operands + Sp loaded direct from global in fragment order.
// LDS: GM (sBh/sBl) + X^T (sXh/sXl) only = 32.8 KB; single barrier.
__global__ __launch_bounds__(256, 3) void k_phase3(
    const float* __restrict__ dtbuf, const float* __restrict__ lac,
    const ushort_t* __restrict__ Bm_h, const ushort_t* __restrict__ Bm_l,
    const ushort_t* __restrict__ Cm_h, const ushort_t* __restrict__ Cm_l,
    const ushort_t* __restrict__ xs_h, const ushort_t* __restrict__ xs_l,
    const ushort_t* __restrict__ Sp_h, const ushort_t* __restrict__ Sp_l,
    const float* __restrict__ Dparam, ushort_t* __restrict__ y16){
  __shared__ __align__(16) ushort_t sBh[64*72], sBl[64*72];   // GM[i][s]
  __shared__ __align__(16) ushort_t sXh[48*72], sXl[48*72];   // X^T[p][s]
  __shared__ float sla[64], sdt[64];
  int tid = threadIdx.x, blk = blockIdx.x;
  int bh = blk>>6, k = blk&63, b = bh>>3, hh = bh&7, t0 = k*64;
  int w = tid>>6, lane = tid&63, l15 = lane&15, quad = lane>>4;

  if (tid < 64){
    sdt[tid] = dtbuf[(size_t)bh*4096 + t0 + tid];
    sla[tid] = lac[(size_t)blk*64 + tid];
  }
  // ---- stage X^T: copy + pack ----
  {
    int s2 = (tid>>3)*2, p0 = (tid&7)*6;
    const ushort_t* xh0 = xs_h + (size_t)(bh*4096+t0+s2)*48 + p0;
    const ushort_t* xl0 = xs_l + (size_t)(bh*4096+t0+s2)*48 + p0;
    #pragma unroll
    for (int c=0;c<6;c++){
      unsigned int hv = (unsigned int)xh0[c] | ((unsigned int)xh0[48+c]<<16);
      unsigned int lv = (unsigned int)xl0[c] | ((unsigned int)xl0[48+c]<<16);
      int o = (p0+c)*72 + s2;
      *(unsigned int*)&sXh[o] = hv;
      *(unsigned int*)&sXl[o] = lv;
    }
  }
  // ---- C fragments direct from global (reused for GM-A and carry-B) ----
  bf16x8 cah[2], cal[2];
  {
    const ushort_t* ch = Cm_h + (size_t)(b*4096+t0+w*16+l15)*64;
    const ushort_t* cl = Cm_l + (size_t)(b*4096+t0+w*16+l15)*64;
    #pragma unroll
    for (int ks=0;ks<2;ks++){
      cah[ks] = *(const bf16x8*)(ch + ks*32 + quad*8);
      cal[ks] = *(const bf16x8*)(cl + ks*32 + quad*8);
    }
  }
  // ---- GM mfma: B fragments direct from global ----
  f32x4 gacc[4];
  #pragma unroll
  for (int t=0;t<4;t++) gacc[t] = (f32x4)(0.f);
  for (int bs=0; bs<=w; ++bs){
    size_t brow = (size_t)(b*4096+t0+bs*16+l15)*64;
    #pragma unroll
    for (int ks=0;ks<2;ks++){
      bf16x8 bhf = *(const bf16x8*)(Bm_h + brow + ks*32 + quad*8);
      bf16x8 blf = *(const bf16x8*)(Bm_l + brow + ks*32 + quad*8);
      gacc[bs] = __builtin_amdgcn_mfma_f32_16x16x32_bf16(cah[ks], bhf, gacc[bs], 0,0,0);
      gacc[bs] = __builtin_amdgcn_mfma_f32_16x16x32_bf16(cah[ks], blf, gacc[bs], 0,0,0);
      gacc[bs] = __builtin_amdgcn_mfma_f32_16x16x32_bf16(cal[ks], bhf, gacc[bs], 0,0,0);
    }
  }
  __syncthreads();   // X^T staging + sdt/sla visible to all waves

  // ---- scale/mask, write GM bf16 hi/lo (wave-local rows); zero tiles ----
  for (int bs=0; bs<=w; ++bs){
    #pragma unroll
    for (int r=0;r<4;r++){
      int i = w*16 + quad*4 + r;
      int s = bs*16 + l15;
      float v = 0.f;
      if (s <= i) v = gacc[bs][r] * __expf(sla[i]-sla[s]) * sdt[s];
      ushort_t hi = f2bf(v);
      sBh[i*72+s] = hi;
      sBl[i*72+s] = f2bf(v - bf2f(hi));
    }
  }
  if (w==0){
    #pragma unroll
    for (int r=0;r<4;r++){ sBh[(quad*4+r)*72 + 16+l15] = 0; sBl[(quad*4+r)*72 + 16+l15] = 0; }
  }
  if (w==2){
    #pragma unroll
    for (int r=0;r<4;r++){ sBh[(32+quad*4+r)*72 + 48+l15] = 0; sBl[(32+quad*4+r)*72 + 48+l15] = 0; }
  }

  // ---- Sp fragments direct (pre-split, [p][n] layout) ----
  bf16x8 pah[3][2], pal[3][2];
  {
    const ushort_t* sph = Sp_h + (size_t)blk*3072;
    const ushort_t* spl = Sp_l + (size_t)blk*3072;
    #pragma unroll
    for (int pt=0;pt<3;pt++)
      #pragma unroll
      for (int ks=0;ks<2;ks++){
        size_t o = (size_t)(pt*16+l15)*64 + ks*32 + quad*8;
        pah[pt][ks] = *(const bf16x8*)(sph + o);
        pal[pt][ks] = *(const bf16x8*)(spl + o);
      }
  }

  // ---- O = X^T·GM^T (intra; GM wave-local in LDS) ----
  f32x4 accI[3], accA[3];
  #pragma unroll
  for (int t=0;t<3;t++){ accI[t] = (f32x4)(0.f); accA[t] = (f32x4)(0.f); }
  int nks = (w>=2) ? 2 : 1;
  for (int ks=0; ks<nks; ++ks){
    int go = (w*16+l15)*72 + ks*32 + quad*8;
    bf16x8 gbh = *(bf16x8*)&sBh[go];
    bf16x8 gbl = *(bf16x8*)&sBl[go];
    #pragma unroll
    for (int pt=0;pt<3;pt++){
      int xo = (pt*16+l15)*72 + ks*32 + quad*8;
      bf16x8 xah = *(bf16x8*)&sXh[xo];
      bf16x8 xal = *(bf16x8*)&sXl[xo];
      accI[pt] = __builtin_amdgcn_mfma_f32_16x16x32_bf16(xah, gbh, accI[pt], 0,0,0);
      accI[pt] = __builtin_amdgcn_mfma_f32_16x16x32_bf16(xah, gbl, accI[pt], 0,0,0);
      accI[pt] = __builtin_amdgcn_mfma_f32_16x16x32_bf16(xal, gbh, accI[pt], 0,0,0);
    }
  }
  // ---- + Sp^T·C^T (carry) ----
  #pragma unroll
  for (int ks=0; ks<2; ++ks){
    #pragma unroll
    for (int pt=0;pt<3;pt++){
      accA[pt] = __builtin_amdgcn_mfma_f32_16x16x32_bf16(pah[pt][ks], cah[ks], accA[pt], 0,0,0);
      accA[pt] = __builtin_amdgcn_mfma_f32_16x16x32_bf16(pah[pt][ks], cal[ks], accA[pt], 0,0,0);
      accA[pt] = __builtin_amdgcn_mfma_f32_16x16x32_bf16(pal[pt][ks], cah[ks], accA[pt], 0,0,0);
    }
  }
  // ---- epilogue: Y[i][p] = accI + exp(la_i)*accA + D*x  -> bf16 ----
  {
    int i = w*16 + l15;
    float eli = __expf(sla[i]);
    float Dh = Dparam[hh];
    ushort_t* ybase = y16 + (size_t)(b*4096+t0+i)*384 + hh*48;
    #pragma unroll
    for (int pt=0;pt<3;pt++)
      #pragma unroll
      for (int r=0;r<4;r++){
        int p = pt*16 + quad*4 + r;
        float xf = bf2f(sXh[p*72 + i]) + bf2f(sXl[p*72 + i]);
        ybase[p] = f2bf(accI[pt][r] + eli*accA[pt][r] + Dh*xf);
      }
  }
}

// ----- gate: per-wave (1 token/wave), z from x (K=4), shuffle RMS; bf16 io -----
__global__ __launch_bounds__(256) void k_gate(
    const float* __restrict__ x, const float* __restrict__ Weff,
    const float* __restrict__ beff,
    const ushort_t* __restrict__ y16, ushort_t* __restrict__ yn16){
  int tid = threadIdx.x;
  int w = tid>>6, lane = tid&63;
  int e0 = lane*6;
  float W0[6],W1v[6],W2v[6],W3v[6],bv[6];
  #pragma unroll
  for (int c=0;c<6;c++){
    int e = e0+c;
    W0[c]=Weff[e]; W1v[c]=Weff[904+e]; W2v[c]=Weff[1808+e]; W3v[c]=Weff[2712+e];
    bv[c]=beff[e];
  }
  #pragma unroll
  for (int t=0;t<4;t++){
    int bl = blockIdx.x*16 + w*4 + t;
    float4 xv = *(const float4*)(x + (size_t)bl*4);
    float g[6]; float ss = 0.f;
    #pragma unroll
    for (int c=0;c<6;c++){
      float zv = bv[c];
      zv = fmaf(xv.x, W0[c], zv);
      zv = fmaf(xv.y, W1v[c], zv);
      zv = fmaf(xv.z, W2v[c], zv);
      zv = fmaf(xv.w, W3v[c], zv);
      float yv = bf2f(y16[(size_t)bl*384 + e0 + c]);
      float gg = yv * (zv * sigmoidf_(zv));
      g[c] = gg; ss += gg*gg;
    }
    #pragma unroll
    for (int off=32; off>0; off>>=1) ss += __shfl_xor(ss, off);
    float rms = rsqrtf(ss*(1.f/384.f) + 1e-5f);
    #pragma unroll
    for (int c=0;c<6;c++)
      yn16[(size_t)bl*384 + e0 + c] = f2bf(g[c]*rms);
  }
}

// ----- mlp2: 64 tokens/block, 2 tokens/thread; yn bf16 input -----
__global__ __launch_bounds__(256) void k_mlp2(
    const ushort_t* __restrict__ yn16, const float* __restrict__ Weff2,
    const float* __restrict__ b1, const float* __restrict__ W2,
    const float* __restrict__ b2, float* __restrict__ macc){
  __shared__ __align__(16) float sW[384][32];
  __shared__ __align__(16) float sm1[64][33];
  __shared__ __align__(16) float sW2[32][32];
  __shared__ __align__(16) float sm2[64][33];
  int tid = threadIdx.x;
  int tok0 = blockIdx.x*64;
  int b = tok0 >> 12;
  #pragma unroll
  for (int r=0;r<12;r++){
    int idx = tid + r*256;
    int row = idx>>3, c4 = (idx&7)*4;
    *(float4*)&sW[row][c4] = *(const float4*)(Weff2 + (size_t)idx*4);
  }
  {
    int row = tid>>3, c4 = (tid&7)*4;
    *(float4*)&sW2[row][c4] = *(const float4*)(W2 + row*32 + c4);
  }
  __syncthreads();
  {
    int tk = tid>>3, j0 = (tid&7)*4;
    float a0[4], a1[4];
    #pragma unroll
    for (int j=0;j<4;j++){ a0[j] = b1[j0+j]; a1[j] = a0[j]; }
    const ushort_t* y0 = yn16 + (size_t)(tok0+tk)*384;
    const ushort_t* y1 = yn16 + (size_t)(tok0+tk+32)*384;
    for (int k8=0;k8<48;k8++){
      ushort_t ua[8], ub[8];
      *(uint4*)ua = *(const uint4*)(y0 + k8*8);
      *(uint4*)ub = *(const uint4*)(y1 + k8*8);
      #pragma unroll
      for (int c=0;c<8;c++){
        float va = bf2f(ua[c]), vb = bf2f(ub[c]);
        float w[4]; *(float4*)w = *(float4*)&sW[k8*8+c][j0];
        #pragma unroll
        for (int j=0;j<4;j++){ a0[j] = fmaf(va, w[j], a0[j]); a1[j] = fmaf(vb, w[j], a1[j]); }
      }
    }
    #pragma unroll
    for (int j=0;j<4;j++){
      sm1[tk][j0+j]    = fmaxf(a0[j], 0.f);
      sm1[tk+32][j0+j] = fmaxf(a1[j], 0.f);
    }
  }
  __syncthreads();
  {
    int tk = tid>>3, j0 = (tid&7)*4;
    float a0[4], a1[4];
    #pragma unroll
    for (int j=0;j<4;j++){ a0[j] = b2[j0+j]; a1[j] = a0[j]; }
    #pragma unroll
    for (int kk=0;kk<32;kk++){
      float va = sm1[tk][kk];
      float vb = sm1[tk+32][kk];
      float w[4]; *(float4*)w = *(float4*)&sW2[kk][j0];
      #pragma unroll
      for (int j=0;j<4;j++){ a0[j] = fmaf(va, w[j], a0[j]); a1[j] = fmaf(vb, w[j], a1[j]); }
    }
    #pragma unroll
    for (int j=0;j<4;j++){
      sm2[tk][j0+j]    = fmaxf(a0[j], 0.f);
      sm2[tk+32][j0+j] = fmaxf(a1[j], 0.f);
    }
  }
  __syncthreads();
  if (tid < 32){
    float t = 0.f;
    #pragma unroll
    for (int tok=0;tok<64;tok++) t += sm2[tok][tid];
    atomicAdd(&macc[b*32 + tid], t);
  }
}

// ----- final: angle[b] = mean_m @ Wo + bo -----
__global__ void k_final(const float* __restrict__ macc, const float* __restrict__ Wo,
                        const float* __restrict__ bo, float* __restrict__ out){
  int tid = threadIdx.x;
  if (tid < 4){
    float acc = bo[0];
    #pragma unroll
    for (int j=0;j<32;j++) acc = fmaf(macc[tid*32+j]*(1.f/4096.f), Wo[j], acc);
    out[tid] = acc;
  }
}

// ---------------------------------------------------------------------------
extern "C" void kernel_launch(void* const* d_in, const int* in_sizes, int n_in,
                              void* d_out, int out_size, void* d_ws, size_t ws_size,
                              hipStream_t stream){
  const float* x      = (const float*)d_in[0];
  const float* Wfc    = (const float*)d_in[1];
  const float* bfc    = (const float*)d_in[2];
  const float* W_in   = (const float*)d_in[3];
  const float* conv_w = (const float*)d_in[4];
  const float* conv_b = (const float*)d_in[5];
  const float* dt_bias= (const float*)d_in[6];
  const float* A_log  = (const float*)d_in[7];
  const float* Dparam = (const float*)d_in[8];
  const float* norm_w = (const float*)d_in[9];
  const float* W_out  = (const float*)d_in[10];
  const float* W1     = (const float*)d_in[11];
  const float* b1     = (const float*)d_in[12];
  const float* W2     = (const float*)d_in[13];
  const float* b2     = (const float*)d_in[14];
  const float* Wo     = (const float*)d_in[15];
  const float* bo     = (const float*)d_in[16];
  float* ws  = (float*)d_ws;
  float* out = (float*)d_out;

  float* Weff  = ws + OFF_W;
  float* beff  = ws + OFF_W + 4096;
  float* Weff2 = ws + OFF_W + 8192;
  ushort_t* yn16 = (ushort_t*)(ws + OFF_Z);
  float* Tb    = ws + OFF_T;
  ushort_t* xs_h = (ushort_t*)(ws + OFF_XS);
  ushort_t* xs_l = xs_h + 6291456u;     // 32*4096*48
  ushort_t* Bm_h = (ushort_t*)(ws + OFF_BM);
  ushort_t* Bm_l = Bm_h + 1048576u;     // 16384*64
  ushort_t* Cm_h = (ushort_t*)(ws + OFF_CM);
  ushort_t* Cm_l = Cm_h + 1048576u;
  float* dtb   = ws + OFF_DT;
  float* lacb  = ws + OFF_LAC;
  ushort_t* Sp_h = (ushort_t*)(ws + OFF_SP);
  ushort_t* Sp_l = Sp_h + 6291456u;     // 2048*3072
  ushort_t* y16 = (ushort_t*)(ws + OFF_Y);
  float* macc  = ws + OFF_MACC;

  k_prep<<<dim3(52), dim3(256), 0, stream>>>(Wfc, bfc, W_in, W_out, W1, norm_w,
                                             Weff, beff, Weff2, macc);
  k_ipc<<<dim3(BL), dim3(256), 0, stream>>>(x, Weff, beff, conv_w, conv_b,
                                            dt_bias, xs_h, xs_l, Bm_h, Bm_l,
                                            Cm_h, Cm_l, dtb);
  k_phase1<<<dim3(BH*NC), dim3(256), 0, stream>>>(dtb, Bm_h, Bm_l, xs_h, xs_l,
                                                  A_log, Tb, lacb);
  k_phase2p<<<dim3(BH,48), dim3(256), 0, stream>>>(Tb, lacb, Sp_h, Sp_l);
  k_phase3<<<dim3(BH*NC), dim3(256), 0, stream>>>(dtb, lacb, Bm_h, Bm_l,
                                                  Cm_h, Cm_l, xs_h, xs_l,
                                                  Sp_h, Sp_l, Dparam, y16);
  k_gate<<<dim3(BL/16), dim3(256), 0, stream>>>(x, Weff, beff, y16, yn16);
  k_mlp2<<<dim3(BL/64), dim3(256), 0, stream>>>(yn16, Weff2, b1, W2, b2, macc);
  k_final<<<dim3(1), dim3(64), 0, stream>>>(macc, Wo, bo, out);
}

// Round 14
// 213.916 us; speedup vs baseline: 1.0104x; 1.0104x over previous
//
#include <hip/hip_runtime.h>
#include <math.h>

// ---------------------------------------------------------------------------
// MambaAnglePredictor — Round 14 (revert R13 direct-load; = R12 +):
//   phase2p emits Sp pre-split bf16 hi/lo; phase3 carry loads them directly
//   norm_w folded into Weff2 (prep); gate writes g*rms
//   phase1 __launch_bounds__(256,4)
// ---------------------------------------------------------------------------

#define BDIM 4
#define LDIM 4096
#define BL (BDIM*LDIM)      // 16384 tokens
#define QC 64
#define NC (LDIM/QC)        // 64
#define BH (BDIM*NH)        // 32
#define NH 8

// workspace offsets (floats)
#define OFF_W    0u          // Weff 4x904 @0, beff @4096, Weff2 @8192
#define OFF_Z    3145728u    // yn bf16
#define OFF_T    9437184u    // T [p][n] per chunk (fp32)
#define OFF_XS   17825792u   // xs_h | xs_l
#define OFF_BM   24117248u   // Bm_h | Bm_l
#define OFF_CM   25165824u   // Cm_h | Cm_l
#define OFF_DT   26214400u   // 32*4096 fp32
#define OFF_LAC  26345472u   // 2048*64 fp32
#define OFF_SP   26476544u   // Sp_h | Sp_l (bf16 hi/lo, [p][n] per chunk)
#define OFF_Y    32768000u   // y bf16
#define OFF_MACC 39059456u   // 4*32

typedef unsigned short ushort_t;
typedef __attribute__((ext_vector_type(8))) short bf16x8;
typedef __attribute__((ext_vector_type(4))) float f32x4;

__device__ __forceinline__ float sigmoidf_(float x){ return 1.0f/(1.0f+__expf(-x)); }
__device__ __forceinline__ ushort_t f2bf(float x){
  unsigned int u = __float_as_uint(x);
  u += 0x7fffu + ((u>>16)&1u);
  return (ushort_t)(u>>16);
}
__device__ __forceinline__ float bf2f(ushort_t h){
  return __uint_as_float(((unsigned int)h)<<16);
}

// ----- prep (merged): Weff, beff, Weff2 (nw-folded), macc zero -----
__global__ void k_prep(const float* __restrict__ Wfc, const float* __restrict__ bfc,
                       const float* __restrict__ W_in, const float* __restrict__ W_out,
                       const float* __restrict__ W1, const float* __restrict__ norm_w,
                       float* __restrict__ Weff, float* __restrict__ beff,
                       float* __restrict__ Weff2, float* __restrict__ macc){
  int blk = blockIdx.x, tid = threadIdx.x;
  if (blk < 4){
    int n = blk*256 + tid;
    if (n >= 904) return;
    float a0=0.f,a1=0.f,a2=0.f,a3=0.f,ab=0.f;
    for (int d=0; d<192; d++){
      float w = W_in[(size_t)d*904 + n];
      a0 = fmaf(Wfc[d], w, a0);
      a1 = fmaf(Wfc[192+d], w, a1);
      a2 = fmaf(Wfc[384+d], w, a2);
      a3 = fmaf(Wfc[576+d], w, a3);
      ab = fmaf(bfc[d], w, ab);
    }
    Weff[n] = a0; Weff[904+n] = a1; Weff[1808+n] = a2; Weff[2712+n] = a3;
    beff[n] = ab;
  } else {
    if (blk == 4 && tid < 128) macc[tid] = 0.f;
    int g = (blk-4)*256 + tid;
    int i = g>>5, j = g&31;
    float a = 0.f;
    for (int d=0; d<192; d++) a = fmaf(W_out[(size_t)i*192+d], W1[d*32+j], a);
    Weff2[g] = a * norm_w[i];
  }
}

// ----- ipc: fused in_proj+conv+silu+dt; outputs pre-split bf16 hi/lo -----
__global__ __launch_bounds__(256) void k_ipc(
    const float* __restrict__ x, const float* __restrict__ Weff,
    const float* __restrict__ beff, const float* __restrict__ conv_w,
    const float* __restrict__ conv_b, const float* __restrict__ dt_bias,
    ushort_t* __restrict__ xs_h, ushort_t* __restrict__ xs_l,
    ushort_t* __restrict__ Bm_h, ushort_t* __restrict__ Bm_l,
    ushort_t* __restrict__ Cm_h, ushort_t* __restrict__ Cm_l,
    float* __restrict__ dtb){
  __shared__ float sx[4][4];
  int bl = blockIdx.x, tid = threadIdx.x;
  int l = bl & 4095, b = bl >> 12;
  if (tid < 16){
    int k = tid>>2, r = tid&3;
    int ll = l-3+k;
    sx[k][r] = (ll>=0) ? x[(size_t)(b*4096+ll)*4 + r] : 0.f;
  }
  __syncthreads();
  if (tid < 8){
    float raw = beff[896+tid];
    #pragma unroll
    for (int r=0;r<4;r++) raw = fmaf(sx[3][r], Weff[r*904+896+tid], raw);
    float xx = raw + dt_bias[tid];
    float dtv = (xx > 20.f) ? xx : log1pf(__expf(xx));
    dtb[(size_t)(b*8+tid)*4096 + l] = dtv;
  }
  #pragma unroll
  for (int half=0; half<2; half++){
    int c = tid + half*256;
    float w0 = Weff[384+c];
    float w1 = Weff[904+384+c];
    float w2 = Weff[1808+384+c];
    float w3 = Weff[2712+384+c];
    float bb = beff[384+c];
    float acc = conv_b[c];
    #pragma unroll
    for (int k=0;k<4;k++){
      int ll = l-3+k;
      float xv = bb;
      xv = fmaf(sx[k][0], w0, xv);
      xv = fmaf(sx[k][1], w1, xv);
      xv = fmaf(sx[k][2], w2, xv);
      xv = fmaf(sx[k][3], w3, xv);
      if (ll < 0) xv = 0.f;
      acc = fmaf(conv_w[k*512+c], xv, acc);
    }
    float v = acc * sigmoidf_(acc);
    ushort_t hi = f2bf(v);
    ushort_t lo = f2bf(v - bf2f(hi));
    if (c < 384){
      int hh = c / 48, p = c - hh*48;
      size_t idx = (size_t)((b*8+hh)*4096 + l)*48 + p;
      xs_h[idx] = hi; xs_l[idx] = lo;
    } else if (c < 448){
      size_t idx = (size_t)bl*64 + (c-384);
      Bm_h[idx] = hi; Bm_l[idx] = lo;
    } else {
      size_t idx = (size_t)bl*64 + (c-448);
      Cm_h[idx] = hi; Cm_l[idx] = lo;
    }
  }
}

// ----- phase1 (MFMA): T^T[p][n] = X^T · Bw per chunk; writes lac -----
__global__ __launch_bounds__(256, 4) void k_phase1(
    const float* __restrict__ dtbuf,
    const ushort_t* __restrict__ Bm_h, const ushort_t* __restrict__ Bm_l,
    const ushort_t* __restrict__ xs_h, const ushort_t* __restrict__ xs_l,
    const float* __restrict__ A_log,
    float* __restrict__ T, float* __restrict__ lac){
  __shared__ __align__(16) ushort_t sBh[64*72], sBl[64*72];   // Bw^T [n][s]
  __shared__ __align__(16) ushort_t sXh[48*72], sXl[48*72];   // X^T [p][s]
  __shared__ float sdt[64], sla[64], sw[64];
  int tid = threadIdx.x, blk = blockIdx.x;
  int bh = blk >> 6, k = blk & 63;
  int b = bh >> 3, hh = bh & 7;
  int t0 = k*64;
  int w = tid>>6, lane = tid&63, l15 = lane&15, quad = lane>>4;

  if (tid < 64) sdt[tid] = dtbuf[(size_t)bh*4096 + t0 + tid];
  __syncthreads();
  if (tid == 0){
    float eA = __expf(A_log[hh]);
    float cum = 0.f;
    for (int i=0;i<64;i++){ cum -= sdt[i]*eA; sla[i] = cum; }
  }
  __syncthreads();
  if (tid < 64){
    sw[tid] = __expf(sla[63]-sla[tid])*sdt[tid];
    lac[(size_t)blk*64 + tid] = sla[tid];
  }
  __syncthreads();
  // ---- stage Bw^T [n][s]: reconstruct, scale by sw, re-split ----
  {
    int s2 = (tid&31)*2, ng = (tid>>5)*8;
    size_t base0 = (size_t)(b*4096+t0+s2)*64 + ng;
    ushort_t h0a[8], l0a[8], h1a[8], l1a[8];
    *(uint4*)h0a = *(const uint4*)(Bm_h + base0);
    *(uint4*)l0a = *(const uint4*)(Bm_l + base0);
    *(uint4*)h1a = *(const uint4*)(Bm_h + base0 + 64);
    *(uint4*)l1a = *(const uint4*)(Bm_l + base0 + 64);
    float w0 = sw[s2], w1 = sw[s2+1];
    #pragma unroll
    for (int c=0;c<8;c++){
      float f0 = (bf2f(h0a[c]) + bf2f(l0a[c])) * w0;
      float f1 = (bf2f(h1a[c]) + bf2f(l1a[c])) * w1;
      ushort_t h0 = f2bf(f0), h1 = f2bf(f1);
      ushort_t lo0 = f2bf(f0-bf2f(h0)), lo1 = f2bf(f1-bf2f(h1));
      int o = (ng+c)*72 + s2;
      *(unsigned int*)&sBh[o] = (unsigned int)h0 | ((unsigned int)h1<<16);
      *(unsigned int*)&sBl[o] = (unsigned int)lo0 | ((unsigned int)lo1<<16);
    }
  }
  // ---- stage X^T [p][s]: pure copy + pack (pre-split) ----
  {
    int s2 = (tid>>3)*2, p0 = (tid&7)*6;
    const ushort_t* xh0 = xs_h + (size_t)(bh*4096+t0+s2)*48 + p0;
    const ushort_t* xl0 = xs_l + (size_t)(bh*4096+t0+s2)*48 + p0;
    #pragma unroll
    for (int c=0;c<6;c++){
      unsigned int hv = (unsigned int)xh0[c] | ((unsigned int)xh0[48+c]<<16);
      unsigned int lv = (unsigned int)xl0[c] | ((unsigned int)xl0[48+c]<<16);
      int o = (p0+c)*72 + s2;
      *(unsigned int*)&sXh[o] = hv;
      *(unsigned int*)&sXl[o] = lv;
    }
  }
  __syncthreads();
  f32x4 acc[3];
  #pragma unroll
  for (int t=0;t<3;t++) acc[t] = (f32x4)(0.f);
  #pragma unroll
  for (int ks=0;ks<2;ks++){
    int bo = (w*16+l15)*72 + ks*32 + quad*8;
    bf16x8 bbh = *(bf16x8*)&sBh[bo];
    bf16x8 bbl = *(bf16x8*)&sBl[bo];
    #pragma unroll
    for (int pt=0;pt<3;pt++){
      int xo = (pt*16+l15)*72 + ks*32 + quad*8;
      bf16x8 xah = *(bf16x8*)&sXh[xo];
      bf16x8 xal = *(bf16x8*)&sXl[xo];
      acc[pt] = __builtin_amdgcn_mfma_f32_16x16x32_bf16(xah, bbh, acc[pt], 0,0,0);
      acc[pt] = __builtin_amdgcn_mfma_f32_16x16x32_bf16(xah, bbl, acc[pt], 0,0,0);
      acc[pt] = __builtin_amdgcn_mfma_f32_16x16x32_bf16(xal, bbh, acc[pt], 0,0,0);
    }
  }
  {
    float* dst = T + (size_t)blk*3072;
    #pragma unroll
    for (int pt=0;pt<3;pt++)
      #pragma unroll
      for (int r=0;r<4;r++)
        dst[(pt*16+quad*4+r)*64 + w*16 + l15] = acc[pt][r];
  }
}

// ----- phase2p: Sp[k] = sum_{j<k} W[k][j] T[j]; emits bf16 hi/lo -----
__global__ __launch_bounds__(256) void k_phase2p(
    const float* __restrict__ T, const float* __restrict__ lac,
    ushort_t* __restrict__ Sp_h, ushort_t* __restrict__ Sp_l){
  __shared__ __align__(16) float sT[64*64];
  __shared__ __align__(16) float sW[64][68];
  __shared__ float sc[64];
  int tid = threadIdx.x;
  int bh = blockIdx.x, es = blockIdx.y;
  #pragma unroll
  for (int r=0;r<4;r++){
    int idx = tid + r*256;
    int row = idx>>4, c4 = (idx&15)*4;
    *(float4*)&sT[row*64 + c4] = *(const float4*)(T + (size_t)(bh*64+row)*3072 + es*64 + c4);
  }
  if (tid < 64) sc[tid] = __expf(lac[(size_t)(bh*64+tid)*64 + 63]);
  __syncthreads();
  if (tid < 64){
    int k = tid;
    float w = 1.f;
    for (int j=63; j>=0; --j){
      bool a = (j < k);
      sW[j][k] = a ? w : 0.f;
      if (a) w *= sc[j];
    }
  }
  __syncthreads();
  int k0 = (tid>>4)*4, e0 = (tid&15)*4;
  float acc[4][4];
  #pragma unroll
  for (int i=0;i<4;i++)
    #pragma unroll
    for (int j=0;j<4;j++) acc[i][j]=0.f;
  int jmax = k0+2; if (jmax > 62) jmax = 62;
  for (int j=0; j<=jmax; ++j){
    float wv[4], tv[4];
    *(float4*)wv = *(float4*)&sW[j][k0];
    *(float4*)tv = *(float4*)&sT[j*64 + e0];
    #pragma unroll
    for (int i=0;i<4;i++)
      #pragma unroll
      for (int e=0;e<4;e++) acc[i][e] = fmaf(wv[i], tv[e], acc[i][e]);
  }
  #pragma unroll
  for (int i=0;i<4;i++){
    ushort4 h4, l4;
    ushort_t* hp = (ushort_t*)&h4;
    ushort_t* lp = (ushort_t*)&l4;
    #pragma unroll
    for (int e=0;e<4;e++){
      ushort_t hi = f2bf(acc[i][e]);
      hp[e] = hi;
      lp[e] = f2bf(acc[i][e] - bf2f(hi));
    }
    size_t o = (size_t)(bh*64+k0+i)*3072 + es*64 + e0;
    *(ushort4*)(Sp_h + o) = h4;
    *(ushort4*)(Sp_l + o) = l4;
  }
}

// ----- phase3 (MFMA, R12 structure): GM = mask(C·B^T)*decay;
//   O = X^T·GM^T + e^la·(Sp^T·C^T) + Dx. Sp frags pre-split direct loads.
__global__ __launch_bounds__(256, 3) void k_phase3(
    const float* __restrict__ dtbuf, const float* __restrict__ lac,
    const ushort_t* __restrict__ Bm_h, const ushort_t* __restrict__ Bm_l,
    const ushort_t* __restrict__ Cm_h, const ushort_t* __restrict__ Cm_l,
    const ushort_t* __restrict__ xs_h, const ushort_t* __restrict__ xs_l,
    const ushort_t* __restrict__ Sp_h, const ushort_t* __restrict__ Sp_l,
    const float* __restrict__ Dparam, ushort_t* __restrict__ y16){
  __shared__ __align__(16) ushort_t sCh[64*72], sCl[64*72];   // C[i][n]
  __shared__ __align__(16) ushort_t sBh[64*72], sBl[64*72];   // B[s][n] -> GM[i][s]
  __shared__ __align__(16) ushort_t sXh[48*72], sXl[48*72];   // X^T[p][s]
  __shared__ float sla[64], sdt[64];
  int tid = threadIdx.x, blk = blockIdx.x;
  int bh = blk>>6, k = blk&63, b = bh>>3, hh = bh&7, t0 = k*64;
  int w = tid>>6, lane = tid&63, l15 = lane&15, quad = lane>>4;

  if (tid < 64){
    sdt[tid] = dtbuf[(size_t)bh*4096 + t0 + tid];
    sla[tid] = lac[(size_t)blk*64 + tid];
  }
  // ---- stage C, B: pure 16B copies ----
  {
    int row = tid>>2, ng = (tid&3)*16;
    size_t gb = (size_t)(b*4096+t0+row)*64 + ng;
    int o = row*72 + ng;
    *(uint4*)&sCh[o]   = *(const uint4*)(Cm_h + gb);
    *(uint4*)&sCh[o+8] = *(const uint4*)(Cm_h + gb + 8);
    *(uint4*)&sCl[o]   = *(const uint4*)(Cm_l + gb);
    *(uint4*)&sCl[o+8] = *(const uint4*)(Cm_l + gb + 8);
    *(uint4*)&sBh[o]   = *(const uint4*)(Bm_h + gb);
    *(uint4*)&sBh[o+8] = *(const uint4*)(Bm_h + gb + 8);
    *(uint4*)&sBl[o]   = *(const uint4*)(Bm_l + gb);
    *(uint4*)&sBl[o+8] = *(const uint4*)(Bm_l + gb + 8);
  }
  // ---- stage X^T: copy + pack ----
  {
    int s2 = (tid>>3)*2, p0 = (tid&7)*6;
    const ushort_t* xh0 = xs_h + (size_t)(bh*4096+t0+s2)*48 + p0;
    const ushort_t* xl0 = xs_l + (size_t)(bh*4096+t0+s2)*48 + p0;
    #pragma unroll
    for (int c=0;c<6;c++){
      unsigned int hv = (unsigned int)xh0[c] | ((unsigned int)xh0[48+c]<<16);
      unsigned int lv = (unsigned int)xl0[c] | ((unsigned int)xl0[48+c]<<16);
      int o = (p0+c)*72 + s2;
      *(unsigned int*)&sXh[o] = hv;
      *(unsigned int*)&sXl[o] = lv;
    }
  }
  __syncthreads();

  // ---- GM mfma: wave w owns i-band w, s-tiles 0..w ----
  f32x4 gacc[4];
  #pragma unroll
  for (int t=0;t<4;t++) gacc[t] = (f32x4)(0.f);
  {
    bf16x8 cah[2], cal[2];
    #pragma unroll
    for (int ks=0;ks<2;ks++){
      int ao = (w*16+l15)*72 + ks*32 + quad*8;
      cah[ks] = *(bf16x8*)&sCh[ao];
      cal[ks] = *(bf16x8*)&sCl[ao];
    }
    for (int bs=0; bs<=w; ++bs){
      #pragma unroll
      for (int ks=0;ks<2;ks++){
        int bo = (bs*16+l15)*72 + ks*32 + quad*8;
        bf16x8 bhf = *(bf16x8*)&sBh[bo];
        bf16x8 blf = *(bf16x8*)&sBl[bo];
        gacc[bs] = __builtin_amdgcn_mfma_f32_16x16x32_bf16(cah[ks], bhf, gacc[bs], 0,0,0);
        gacc[bs] = __builtin_amdgcn_mfma_f32_16x16x32_bf16(cah[ks], blf, gacc[bs], 0,0,0);
        gacc[bs] = __builtin_amdgcn_mfma_f32_16x16x32_bf16(cal[ks], bhf, gacc[bs], 0,0,0);
      }
    }
  }
  __syncthreads();   // sB reads done -> safe to overwrite with GM

  // ---- scale/mask, write GM bf16 hi/lo into sBh/sBl; zero needed tiles ----
  for (int bs=0; bs<=w; ++bs){
    #pragma unroll
    for (int r=0;r<4;r++){
      int i = w*16 + quad*4 + r;
      int s = bs*16 + l15;
      float v = 0.f;
      if (s <= i) v = gacc[bs][r] * __expf(sla[i]-sla[s]) * sdt[s];
      ushort_t hi = f2bf(v);
      sBh[i*72+s] = hi;
      sBl[i*72+s] = f2bf(v - bf2f(hi));
    }
  }
  if (w==0){
    #pragma unroll
    for (int r=0;r<4;r++){ sBh[(quad*4+r)*72 + 16+l15] = 0; sBl[(quad*4+r)*72 + 16+l15] = 0; }
  }
  if (w==2){
    #pragma unroll
    for (int r=0;r<4;r++){ sBh[(32+quad*4+r)*72 + 48+l15] = 0; sBl[(32+quad*4+r)*72 + 48+l15] = 0; }
  }
  __syncthreads();

  // ---- Sp fragments direct (pre-split, [p][n] layout) ----
  bf16x8 pah[3][2], pal[3][2];
  {
    const ushort_t* sph = Sp_h + (size_t)blk*3072;
    const ushort_t* spl = Sp_l + (size_t)blk*3072;
    #pragma unroll
    for (int pt=0;pt<3;pt++)
      #pragma unroll
      for (int ks=0;ks<2;ks++){
        size_t o = (size_t)(pt*16+l15)*64 + ks*32 + quad*8;
        pah[pt][ks] = *(const bf16x8*)(sph + o);
        pal[pt][ks] = *(const bf16x8*)(spl + o);
      }
  }

  // ---- O = X^T·GM^T (intra) ----
  f32x4 accI[3], accA[3];
  #pragma unroll
  for (int t=0;t<3;t++){ accI[t] = (f32x4)(0.f); accA[t] = (f32x4)(0.f); }
  int nks = (w>=2) ? 2 : 1;
  for (int ks=0; ks<nks; ++ks){
    int go = (w*16+l15)*72 + ks*32 + quad*8;
    bf16x8 gbh = *(bf16x8*)&sBh[go];
    bf16x8 gbl = *(bf16x8*)&sBl[go];
    #pragma unroll
    for (int pt=0;pt<3;pt++){
      int xo = (pt*16+l15)*72 + ks*32 + quad*8;
      bf16x8 xah = *(bf16x8*)&sXh[xo];
      bf16x8 xal = *(bf16x8*)&sXl[xo];
      accI[pt] = __builtin_amdgcn_mfma_f32_16x16x32_bf16(xah, gbh, accI[pt], 0,0,0);
      accI[pt] = __builtin_amdgcn_mfma_f32_16x16x32_bf16(xah, gbl, accI[pt], 0,0,0);
      accI[pt] = __builtin_amdgcn_mfma_f32_16x16x32_bf16(xal, gbh, accI[pt], 0,0,0);
    }
  }
  // ---- + Sp^T·C^T (carry), Sp frags from registers ----
  #pragma unroll
  for (int ks=0; ks<2; ++ks){
    int co = (w*16+l15)*72 + ks*32 + quad*8;
    bf16x8 cbh = *(bf16x8*)&sCh[co];
    bf16x8 cbl = *(bf16x8*)&sCl[co];
    #pragma unroll
    for (int pt=0;pt<3;pt++){
      accA[pt] = __builtin_amdgcn_mfma_f32_16x16x32_bf16(pah[pt][ks], cbh, accA[pt], 0,0,0);
      accA[pt] = __builtin_amdgcn_mfma_f32_16x16x32_bf16(pah[pt][ks], cbl, accA[pt], 0,0,0);
      accA[pt] = __builtin_amdgcn_mfma_f32_16x16x32_bf16(pal[pt][ks], cbh, accA[pt], 0,0,0);
    }
  }
  // ---- epilogue: Y[i][p] = accI + exp(la_i)*accA + D*x  -> bf16 ----
  {
    int i = w*16 + l15;
    float eli = __expf(sla[i]);
    float Dh = Dparam[hh];
    ushort_t* ybase = y16 + (size_t)(b*4096+t0+i)*384 + hh*48;
    #pragma unroll
    for (int pt=0;pt<3;pt++)
      #pragma unroll
      for (int r=0;r<4;r++){
        int p = pt*16 + quad*4 + r;
        float xf = bf2f(sXh[p*72 + i]) + bf2f(sXl[p*72 + i]);
        ybase[p] = f2bf(accI[pt][r] + eli*accA[pt][r] + Dh*xf);
      }
  }
}

// ----- gate: per-wave (1 token/wave), z from x (K=4), shuffle RMS; bf16 io -----
__global__ __launch_bounds__(256) void k_gate(
    const float* __restrict__ x, const float* __restrict__ Weff,
    const float* __restrict__ beff,
    const ushort_t* __restrict__ y16, ushort_t* __restrict__ yn16){
  int tid = threadIdx.x;
  int w = tid>>6, lane = tid&63;
  int e0 = lane*6;
  float W0[6],W1v[6],W2v[6],W3v[6],bv[6];
  #pragma unroll
  for (int c=0;c<6;c++){
    int e = e0+c;
    W0[c]=Weff[e]; W1v[c]=Weff[904+e]; W2v[c]=Weff[1808+e]; W3v[c]=Weff[2712+e];
    bv[c]=beff[e];
  }
  #pragma unroll
  for (int t=0;t<4;t++){
    int bl = blockIdx.x*16 + w*4 + t;
    float4 xv = *(const float4*)(x + (size_t)bl*4);
    float g[6]; float ss = 0.f;
    #pragma unroll
    for (int c=0;c<6;c++){
      float zv = bv[c];
      zv = fmaf(xv.x, W0[c], zv);
      zv = fmaf(xv.y, W1v[c], zv);
      zv = fmaf(xv.z, W2v[c], zv);
      zv = fmaf(xv.w, W3v[c], zv);
      float yv = bf2f(y16[(size_t)bl*384 + e0 + c]);
      float gg = yv * (zv * sigmoidf_(zv));
      g[c] = gg; ss += gg*gg;
    }
    #pragma unroll
    for (int off=32; off>0; off>>=1) ss += __shfl_xor(ss, off);
    float rms = rsqrtf(ss*(1.f/384.f) + 1e-5f);
    #pragma unroll
    for (int c=0;c<6;c++)
      yn16[(size_t)bl*384 + e0 + c] = f2bf(g[c]*rms);
  }
}

// ----- mlp2: 64 tokens/block, 2 tokens/thread; yn bf16 input -----
__global__ __launch_bounds__(256) void k_mlp2(
    const ushort_t* __restrict__ yn16, const float* __restrict__ Weff2,
    const float* __restrict__ b1, const float* __restrict__ W2,
    const float* __restrict__ b2, float* __restrict__ macc){
  __shared__ __align__(16) float sW[384][32];
  __shared__ __align__(16) float sm1[64][33];
  __shared__ __align__(16) float sW2[32][32];
  __shared__ __align__(16) float sm2[64][33];
  int tid = threadIdx.x;
  int tok0 = blockIdx.x*64;
  int b = tok0 >> 12;
  #pragma unroll
  for (int r=0;r<12;r++){
    int idx = tid + r*256;
    int row = idx>>3, c4 = (idx&7)*4;
    *(float4*)&sW[row][c4] = *(const float4*)(Weff2 + (size_t)idx*4);
  }
  {
    int row = tid>>3, c4 = (tid&7)*4;
    *(float4*)&sW2[row][c4] = *(const float4*)(W2 + row*32 + c4);
  }
  __syncthreads();
  {
    int tk = tid>>3, j0 = (tid&7)*4;
    float a0[4], a1[4];
    #pragma unroll
    for (int j=0;j<4;j++){ a0[j] = b1[j0+j]; a1[j] = a0[j]; }
    const ushort_t* y0 = yn16 + (size_t)(tok0+tk)*384;
    const ushort_t* y1 = yn16 + (size_t)(tok0+tk+32)*384;
    for (int k8=0;k8<48;k8++){
      ushort_t ua[8], ub[8];
      *(uint4*)ua = *(const uint4*)(y0 + k8*8);
      *(uint4*)ub = *(const uint4*)(y1 + k8*8);
      #pragma unroll
      for (int c=0;c<8;c++){
        float va = bf2f(ua[c]), vb = bf2f(ub[c]);
        float w[4]; *(float4*)w = *(float4*)&sW[k8*8+c][j0];
        #pragma unroll
        for (int j=0;j<4;j++){ a0[j] = fmaf(va, w[j], a0[j]); a1[j] = fmaf(vb, w[j], a1[j]); }
      }
    }
    #pragma unroll
    for (int j=0;j<4;j++){
      sm1[tk][j0+j]    = fmaxf(a0[j], 0.f);
      sm1[tk+32][j0+j] = fmaxf(a1[j], 0.f);
    }
  }
  __syncthreads();
  {
    int tk = tid>>3, j0 = (tid&7)*4;
    float a0[4], a1[4];
    #pragma unroll
    for (int j=0;j<4;j++){ a0[j] = b2[j0+j]; a1[j] = a0[j]; }
    #pragma unroll
    for (int kk=0;kk<32;kk++){
      float va = sm1[tk][kk];
      float vb = sm1[tk+32][kk];
      float w[4]; *(float4*)w = *(float4*)&sW2[kk][j0];
      #pragma unroll
      for (int j=0;j<4;j++){ a0[j] = fmaf(va, w[j], a0[j]); a1[j] = fmaf(vb, w[j], a1[j]); }
    }
    #pragma unroll
    for (int j=0;j<4;j++){
      sm2[tk][j0+j]    = fmaxf(a0[j], 0.f);
      sm2[tk+32][j0+j] = fmaxf(a1[j], 0.f);
    }
  }
  __syncthreads();
  if (tid < 32){
    float t = 0.f;
    #pragma unroll
    for (int tok=0;tok<64;tok++) t += sm2[tok][tid];
    atomicAdd(&macc[b*32 + tid], t);
  }
}

// ----- final: angle[b] = mean_m @ Wo + bo -----
__global__ void k_final(const float* __restrict__ macc, const float* __restrict__ Wo,
                        const float* __restrict__ bo, float* __restrict__ out){
  int tid = threadIdx.x;
  if (tid < 4){
    float acc = bo[0];
    #pragma unroll
    for (int j=0;j<32;j++) acc = fmaf(macc[tid*32+j]*(1.f/4096.f), Wo[j], acc);
    out[tid] = acc;
  }
}

// ---------------------------------------------------------------------------
extern "C" void kernel_launch(void* const* d_in, const int* in_sizes, int n_in,
                              void* d_out, int out_size, void* d_ws, size_t ws_size,
                              hipStream_t stream){
  const float* x      = (const float*)d_in[0];
  const float* Wfc    = (const float*)d_in[1];
  const float* bfc    = (const float*)d_in[2];
  const float* W_in   = (const float*)d_in[3];
  const float* conv_w = (const float*)d_in[4];
  const float* conv_b = (const float*)d_in[5];
  const float* dt_bias= (const float*)d_in[6];
  const float* A_log  = (const float*)d_in[7];
  const float* Dparam = (const float*)d_in[8];
  const float* norm_w = (const float*)d_in[9];
  const float* W_out  = (const float*)d_in[10];
  const float* W1     = (const float*)d_in[11];
  const float* b1     = (const float*)d_in[12];
  const float* W2     = (const float*)d_in[13];
  const float* b2     = (const float*)d_in[14];
  const float* Wo     = (const float*)d_in[15];
  const float* bo     = (const float*)d_in[16];
  float* ws  = (float*)d_ws;
  float* out = (float*)d_out;

  float* Weff  = ws + OFF_W;
  float* beff  = ws + OFF_W + 4096;
  float* Weff2 = ws + OFF_W + 8192;
  ushort_t* yn16 = (ushort_t*)(ws + OFF_Z);
  float* Tb    = ws + OFF_T;
  ushort_t* xs_h = (ushort_t*)(ws + OFF_XS);
  ushort_t* xs_l = xs_h + 6291456u;     // 32*4096*48
  ushort_t* Bm_h = (ushort_t*)(ws + OFF_BM);
  ushort_t* Bm_l = Bm_h + 1048576u;     // 16384*64
  ushort_t* Cm_h = (ushort_t*)(ws + OFF_CM);
  ushort_t* Cm_l = Cm_h + 1048576u;
  float* dtb   = ws + OFF_DT;
  float* lacb  = ws + OFF_LAC;
  ushort_t* Sp_h = (ushort_t*)(ws + OFF_SP);
  ushort_t* Sp_l = Sp_h + 6291456u;     // 2048*3072
  ushort_t* y16 = (ushort_t*)(ws + OFF_Y);
  float* macc  = ws + OFF_MACC;

  k_prep<<<dim3(52), dim3(256), 0, stream>>>(Wfc, bfc, W_in, W_out, W1, norm_w,
                                             Weff, beff, Weff2, macc);
  k_ipc<<<dim3(BL), dim3(256), 0, stream>>>(x, Weff, beff, conv_w, conv_b,
                                            dt_bias, xs_h, xs_l, Bm_h, Bm_l,
                                            Cm_h, Cm_l, dtb);
  k_phase1<<<dim3(BH*NC), dim3(256), 0, stream>>>(dtb, Bm_h, Bm_l, xs_h, xs_l,
                                                  A_log, Tb, lacb);
  k_phase2p<<<dim3(BH,48), dim3(256), 0, stream>>>(Tb, lacb, Sp_h, Sp_l);
  k_phase3<<<dim3(BH*NC), dim3(256), 0, stream>>>(dtb, lacb, Bm_h, Bm_l,
                                                  Cm_h, Cm_l, xs_h, xs_l,
                                                  Sp_h, Sp_l, Dparam, y16);
  k_gate<<<dim3(BL/16), dim3(256), 0, stream>>>(x, Weff, beff, y16, yn16);
  k_mlp2<<<dim3(BL/64), dim3(256), 0, stream>>>(yn16, Weff2, b1, W2, b2, macc);
  k_final<<<dim3(1), dim3(64), 0, stream>>>(macc, Wo, bo, out);
}

// Round 15
// 199.290 us; speedup vs baseline: 1.0845x; 1.0734x over previous
//
#include <hip/hip_runtime.h>
#include <math.h>

// ---------------------------------------------------------------------------
// MambaAnglePredictor — Round 15 (R14 with phase1 back to (256,3); ipc 2-token):
//   ipc: 2 tokens/block — weights loaded once per channel for both tokens
//   phase2p emits Sp pre-split bf16 hi/lo; phase3 carry loads them directly
//   norm_w folded into Weff2; gate writes g*rms
// ---------------------------------------------------------------------------

#define BDIM 4
#define LDIM 4096
#define BL (BDIM*LDIM)      // 16384 tokens
#define QC 64
#define NC (LDIM/QC)        // 64
#define BH (BDIM*NH)        // 32
#define NH 8

// workspace offsets (floats)
#define OFF_W    0u          // Weff 4x904 @0, beff @4096, Weff2 @8192
#define OFF_Z    3145728u    // yn bf16
#define OFF_T    9437184u    // T [p][n] per chunk (fp32)
#define OFF_XS   17825792u   // xs_h | xs_l
#define OFF_BM   24117248u   // Bm_h | Bm_l
#define OFF_CM   25165824u   // Cm_h | Cm_l
#define OFF_DT   26214400u   // 32*4096 fp32
#define OFF_LAC  26345472u   // 2048*64 fp32
#define OFF_SP   26476544u   // Sp_h | Sp_l (bf16 hi/lo, [p][n] per chunk)
#define OFF_Y    32768000u   // y bf16
#define OFF_MACC 39059456u   // 4*32

typedef unsigned short ushort_t;
typedef __attribute__((ext_vector_type(8))) short bf16x8;
typedef __attribute__((ext_vector_type(4))) float f32x4;

__device__ __forceinline__ float sigmoidf_(float x){ return 1.0f/(1.0f+__expf(-x)); }
__device__ __forceinline__ ushort_t f2bf(float x){
  unsigned int u = __float_as_uint(x);
  u += 0x7fffu + ((u>>16)&1u);
  return (ushort_t)(u>>16);
}
__device__ __forceinline__ float bf2f(ushort_t h){
  return __uint_as_float(((unsigned int)h)<<16);
}

// ----- prep (merged): Weff, beff, Weff2 (nw-folded), macc zero -----
__global__ void k_prep(const float* __restrict__ Wfc, const float* __restrict__ bfc,
                       const float* __restrict__ W_in, const float* __restrict__ W_out,
                       const float* __restrict__ W1, const float* __restrict__ norm_w,
                       float* __restrict__ Weff, float* __restrict__ beff,
                       float* __restrict__ Weff2, float* __restrict__ macc){
  int blk = blockIdx.x, tid = threadIdx.x;
  if (blk < 4){
    int n = blk*256 + tid;
    if (n >= 904) return;
    float a0=0.f,a1=0.f,a2=0.f,a3=0.f,ab=0.f;
    for (int d=0; d<192; d++){
      float w = W_in[(size_t)d*904 + n];
      a0 = fmaf(Wfc[d], w, a0);
      a1 = fmaf(Wfc[192+d], w, a1);
      a2 = fmaf(Wfc[384+d], w, a2);
      a3 = fmaf(Wfc[576+d], w, a3);
      ab = fmaf(bfc[d], w, ab);
    }
    Weff[n] = a0; Weff[904+n] = a1; Weff[1808+n] = a2; Weff[2712+n] = a3;
    beff[n] = ab;
  } else {
    if (blk == 4 && tid < 128) macc[tid] = 0.f;
    int g = (blk-4)*256 + tid;
    int i = g>>5, j = g&31;
    float a = 0.f;
    for (int d=0; d<192; d++) a = fmaf(W_out[(size_t)i*192+d], W1[d*32+j], a);
    Weff2[g] = a * norm_w[i];
  }
}

// ----- ipc: fused in_proj+conv+silu+dt; 2 tokens/block, weights loaded once -----
__global__ __launch_bounds__(256) void k_ipc(
    const float* __restrict__ x, const float* __restrict__ Weff,
    const float* __restrict__ beff, const float* __restrict__ conv_w,
    const float* __restrict__ conv_b, const float* __restrict__ dt_bias,
    ushort_t* __restrict__ xs_h, ushort_t* __restrict__ xs_l,
    ushort_t* __restrict__ Bm_h, ushort_t* __restrict__ Bm_l,
    ushort_t* __restrict__ Cm_h, ushort_t* __restrict__ Cm_l,
    float* __restrict__ dtb){
  __shared__ float sx[5][4];            // x rows l0-3 .. l0+1
  int pb = blockIdx.x, tid = threadIdx.x;
  int bl0 = pb*2;
  int l0 = bl0 & 4095, b = bl0 >> 12;
  if (tid < 20){
    int row = tid>>2, r = tid&3;
    int ll = l0-3+row;
    sx[row][r] = (ll>=0) ? x[(size_t)(b*4096+ll)*4 + r] : 0.f;
  }
  __syncthreads();
  if (tid < 16){
    int t = tid>>3, hh = tid&7;
    float raw = beff[896+hh];
    #pragma unroll
    for (int r=0;r<4;r++) raw = fmaf(sx[3+t][r], Weff[r*904+896+hh], raw);
    float xx = raw + dt_bias[hh];
    float dtv = (xx > 20.f) ? xx : log1pf(__expf(xx));
    dtb[(size_t)(b*8+hh)*4096 + l0 + t] = dtv;
  }
  #pragma unroll
  for (int half=0; half<2; half++){
    int c = tid + half*256;
    float w0 = Weff[384+c];
    float w1 = Weff[904+384+c];
    float w2 = Weff[1808+384+c];
    float w3 = Weff[2712+384+c];
    float bb = beff[384+c];
    float cw0 = conv_w[c], cw1 = conv_w[512+c], cw2 = conv_w[1024+c], cw3 = conv_w[1536+c];
    float cb = conv_b[c];
    float pre[5];
    #pragma unroll
    for (int q=0;q<5;q++){
      int ll = l0-3+q;
      float xv = bb;
      xv = fmaf(sx[q][0], w0, xv);
      xv = fmaf(sx[q][1], w1, xv);
      xv = fmaf(sx[q][2], w2, xv);
      xv = fmaf(sx[q][3], w3, xv);
      pre[q] = (ll >= 0) ? xv : 0.f;
    }
    float a0 = cb, a1 = cb;
    a0 = fmaf(cw0,pre[0],a0); a0 = fmaf(cw1,pre[1],a0);
    a0 = fmaf(cw2,pre[2],a0); a0 = fmaf(cw3,pre[3],a0);
    a1 = fmaf(cw0,pre[1],a1); a1 = fmaf(cw1,pre[2],a1);
    a1 = fmaf(cw2,pre[3],a1); a1 = fmaf(cw3,pre[4],a1);
    float v0 = a0 * sigmoidf_(a0);
    float v1 = a1 * sigmoidf_(a1);
    ushort_t h0 = f2bf(v0), lo0t = f2bf(v0 - bf2f(h0));
    ushort_t h1 = f2bf(v1), lo1t = f2bf(v1 - bf2f(h1));
    if (c < 384){
      int hh = c / 48, p = c - hh*48;
      size_t idx = (size_t)((b*8+hh)*4096 + l0)*48 + p;
      xs_h[idx] = h0; xs_l[idx] = lo0t;
      xs_h[idx+48] = h1; xs_l[idx+48] = lo1t;
    } else if (c < 448){
      size_t idx = (size_t)bl0*64 + (c-384);
      Bm_h[idx] = h0; Bm_l[idx] = lo0t;
      Bm_h[idx+64] = h1; Bm_l[idx+64] = lo1t;
    } else {
      size_t idx = (size_t)bl0*64 + (c-448);
      Cm_h[idx] = h0; Cm_l[idx] = lo0t;
      Cm_h[idx+64] = h1; Cm_l[idx+64] = lo1t;
    }
  }
}

// ----- phase1 (MFMA): T^T[p][n] = X^T · Bw per chunk; writes lac -----
__global__ __launch_bounds__(256, 3) void k_phase1(
    const float* __restrict__ dtbuf,
    const ushort_t* __restrict__ Bm_h, const ushort_t* __restrict__ Bm_l,
    const ushort_t* __restrict__ xs_h, const ushort_t* __restrict__ xs_l,
    const float* __restrict__ A_log,
    float* __restrict__ T, float* __restrict__ lac){
  __shared__ __align__(16) ushort_t sBh[64*72], sBl[64*72];   // Bw^T [n][s]
  __shared__ __align__(16) ushort_t sXh[48*72], sXl[48*72];   // X^T [p][s]
  __shared__ float sdt[64], sla[64], sw[64];
  int tid = threadIdx.x, blk = blockIdx.x;
  int bh = blk >> 6, k = blk & 63;
  int b = bh >> 3, hh = bh & 7;
  int t0 = k*64;
  int w = tid>>6, lane = tid&63, l15 = lane&15, quad = lane>>4;

  if (tid < 64) sdt[tid] = dtbuf[(size_t)bh*4096 + t0 + tid];
  __syncthreads();
  if (tid == 0){
    float eA = __expf(A_log[hh]);
    float cum = 0.f;
    for (int i=0;i<64;i++){ cum -= sdt[i]*eA; sla[i] = cum; }
  }
  __syncthreads();
  if (tid < 64){
    sw[tid] = __expf(sla[63]-sla[tid])*sdt[tid];
    lac[(size_t)blk*64 + tid] = sla[tid];
  }
  __syncthreads();
  // ---- stage Bw^T [n][s]: reconstruct, scale by sw, re-split ----
  {
    int s2 = (tid&31)*2, ng = (tid>>5)*8;
    size_t base0 = (size_t)(b*4096+t0+s2)*64 + ng;
    ushort_t h0a[8], l0a[8], h1a[8], l1a[8];
    *(uint4*)h0a = *(const uint4*)(Bm_h + base0);
    *(uint4*)l0a = *(const uint4*)(Bm_l + base0);
    *(uint4*)h1a = *(const uint4*)(Bm_h + base0 + 64);
    *(uint4*)l1a = *(const uint4*)(Bm_l + base0 + 64);
    float w0 = sw[s2], w1 = sw[s2+1];
    #pragma unroll
    for (int c=0;c<8;c++){
      float f0 = (bf2f(h0a[c]) + bf2f(l0a[c])) * w0;
      float f1 = (bf2f(h1a[c]) + bf2f(l1a[c])) * w1;
      ushort_t h0 = f2bf(f0), h1 = f2bf(f1);
      ushort_t lo0 = f2bf(f0-bf2f(h0)), lo1 = f2bf(f1-bf2f(h1));
      int o = (ng+c)*72 + s2;
      *(unsigned int*)&sBh[o] = (unsigned int)h0 | ((unsigned int)h1<<16);
      *(unsigned int*)&sBl[o] = (unsigned int)lo0 | ((unsigned int)lo1<<16);
    }
  }
  // ---- stage X^T [p][s]: pure copy + pack (pre-split) ----
  {
    int s2 = (tid>>3)*2, p0 = (tid&7)*6;
    const ushort_t* xh0 = xs_h + (size_t)(bh*4096+t0+s2)*48 + p0;
    const ushort_t* xl0 = xs_l + (size_t)(bh*4096+t0+s2)*48 + p0;
    #pragma unroll
    for (int c=0;c<6;c++){
      unsigned int hv = (unsigned int)xh0[c] | ((unsigned int)xh0[48+c]<<16);
      unsigned int lv = (unsigned int)xl0[c] | ((unsigned int)xl0[48+c]<<16);
      int o = (p0+c)*72 + s2;
      *(unsigned int*)&sXh[o] = hv;
      *(unsigned int*)&sXl[o] = lv;
    }
  }
  __syncthreads();
  f32x4 acc[3];
  #pragma unroll
  for (int t=0;t<3;t++) acc[t] = (f32x4)(0.f);
  #pragma unroll
  for (int ks=0;ks<2;ks++){
    int bo = (w*16+l15)*72 + ks*32 + quad*8;
    bf16x8 bbh = *(bf16x8*)&sBh[bo];
    bf16x8 bbl = *(bf16x8*)&sBl[bo];
    #pragma unroll
    for (int pt=0;pt<3;pt++){
      int xo = (pt*16+l15)*72 + ks*32 + quad*8;
      bf16x8 xah = *(bf16x8*)&sXh[xo];
      bf16x8 xal = *(bf16x8*)&sXl[xo];
      acc[pt] = __builtin_amdgcn_mfma_f32_16x16x32_bf16(xah, bbh, acc[pt], 0,0,0);
      acc[pt] = __builtin_amdgcn_mfma_f32_16x16x32_bf16(xah, bbl, acc[pt], 0,0,0);
      acc[pt] = __builtin_amdgcn_mfma_f32_16x16x32_bf16(xal, bbh, acc[pt], 0,0,0);
    }
  }
  {
    float* dst = T + (size_t)blk*3072;
    #pragma unroll
    for (int pt=0;pt<3;pt++)
      #pragma unroll
      for (int r=0;r<4;r++)
        dst[(pt*16+quad*4+r)*64 + w*16 + l15] = acc[pt][r];
  }
}

// ----- phase2p: Sp[k] = sum_{j<k} W[k][j] T[j]; emits bf16 hi/lo -----
__global__ __launch_bounds__(256) void k_phase2p(
    const float* __restrict__ T, const float* __restrict__ lac,
    ushort_t* __restrict__ Sp_h, ushort_t* __restrict__ Sp_l){
  __shared__ __align__(16) float sT[64*64];
  __shared__ __align__(16) float sW[64][68];
  __shared__ float sc[64];
  int tid = threadIdx.x;
  int bh = blockIdx.x, es = blockIdx.y;
  #pragma unroll
  for (int r=0;r<4;r++){
    int idx = tid + r*256;
    int row = idx>>4, c4 = (idx&15)*4;
    *(float4*)&sT[row*64 + c4] = *(const float4*)(T + (size_t)(bh*64+row)*3072 + es*64 + c4);
  }
  if (tid < 64) sc[tid] = __expf(lac[(size_t)(bh*64+tid)*64 + 63]);
  __syncthreads();
  if (tid < 64){
    int k = tid;
    float w = 1.f;
    for (int j=63; j>=0; --j){
      bool a = (j < k);
      sW[j][k] = a ? w : 0.f;
      if (a) w *= sc[j];
    }
  }
  __syncthreads();
  int k0 = (tid>>4)*4, e0 = (tid&15)*4;
  float acc[4][4];
  #pragma unroll
  for (int i=0;i<4;i++)
    #pragma unroll
    for (int j=0;j<4;j++) acc[i][j]=0.f;
  int jmax = k0+2; if (jmax > 62) jmax = 62;
  for (int j=0; j<=jmax; ++j){
    float wv[4], tv[4];
    *(float4*)wv = *(float4*)&sW[j][k0];
    *(float4*)tv = *(float4*)&sT[j*64 + e0];
    #pragma unroll
    for (int i=0;i<4;i++)
      #pragma unroll
      for (int e=0;e<4;e++) acc[i][e] = fmaf(wv[i], tv[e], acc[i][e]);
  }
  #pragma unroll
  for (int i=0;i<4;i++){
    ushort4 h4, l4;
    ushort_t* hp = (ushort_t*)&h4;
    ushort_t* lp = (ushort_t*)&l4;
    #pragma unroll
    for (int e=0;e<4;e++){
      ushort_t hi = f2bf(acc[i][e]);
      hp[e] = hi;
      lp[e] = f2bf(acc[i][e] - bf2f(hi));
    }
    size_t o = (size_t)(bh*64+k0+i)*3072 + es*64 + e0;
    *(ushort4*)(Sp_h + o) = h4;
    *(ushort4*)(Sp_l + o) = l4;
  }
}

// ----- phase3 (MFMA): GM = mask(C·B^T)*decay;
//   O = X^T·GM^T + e^la·(Sp^T·C^T) + Dx. Sp frags pre-split direct loads.
__global__ __launch_bounds__(256, 3) void k_phase3(
    const float* __restrict__ dtbuf, const float* __restrict__ lac,
    const ushort_t* __restrict__ Bm_h, const ushort_t* __restrict__ Bm_l,
    const ushort_t* __restrict__ Cm_h, const ushort_t* __restrict__ Cm_l,
    const ushort_t* __restrict__ xs_h, const ushort_t* __restrict__ xs_l,
    const ushort_t* __restrict__ Sp_h, const ushort_t* __restrict__ Sp_l,
    const float* __restrict__ Dparam, ushort_t* __restrict__ y16){
  __shared__ __align__(16) ushort_t sCh[64*72], sCl[64*72];   // C[i][n]
  __shared__ __align__(16) ushort_t sBh[64*72], sBl[64*72];   // B[s][n] -> GM[i][s]
  __shared__ __align__(16) ushort_t sXh[48*72], sXl[48*72];   // X^T[p][s]
  __shared__ float sla[64], sdt[64];
  int tid = threadIdx.x, blk = blockIdx.x;
  int bh = blk>>6, k = blk&63, b = bh>>3, hh = bh&7, t0 = k*64;
  int w = tid>>6, lane = tid&63, l15 = lane&15, quad = lane>>4;

  if (tid < 64){
    sdt[tid] = dtbuf[(size_t)bh*4096 + t0 + tid];
    sla[tid] = lac[(size_t)blk*64 + tid];
  }
  // ---- stage C, B: pure 16B copies ----
  {
    int row = tid>>2, ng = (tid&3)*16;
    size_t gb = (size_t)(b*4096+t0+row)*64 + ng;
    int o = row*72 + ng;
    *(uint4*)&sCh[o]   = *(const uint4*)(Cm_h + gb);
    *(uint4*)&sCh[o+8] = *(const uint4*)(Cm_h + gb + 8);
    *(uint4*)&sCl[o]   = *(const uint4*)(Cm_l + gb);
    *(uint4*)&sCl[o+8] = *(const uint4*)(Cm_l + gb + 8);
    *(uint4*)&sBh[o]   = *(const uint4*)(Bm_h + gb);
    *(uint4*)&sBh[o+8] = *(const uint4*)(Bm_h + gb + 8);
    *(uint4*)&sBl[o]   = *(const uint4*)(Bm_l + gb);
    *(uint4*)&sBl[o+8] = *(const uint4*)(Bm_l + gb + 8);
  }
  // ---- stage X^T: copy + pack ----
  {
    int s2 = (tid>>3)*2, p0 = (tid&7)*6;
    const ushort_t* xh0 = xs_h + (size_t)(bh*4096+t0+s2)*48 + p0;
    const ushort_t* xl0 = xs_l + (size_t)(bh*4096+t0+s2)*48 + p0;
    #pragma unroll
    for (int c=0;c<6;c++){
      unsigned int hv = (unsigned int)xh0[c] | ((unsigned int)xh0[48+c]<<16);
      unsigned int lv = (unsigned int)xl0[c] | ((unsigned int)xl0[48+c]<<16);
      int o = (p0+c)*72 + s2;
      *(unsigned int*)&sXh[o] = hv;
      *(unsigned int*)&sXl[o] = lv;
    }
  }
  __syncthreads();

  // ---- GM mfma: wave w owns i-band w, s-tiles 0..w ----
  f32x4 gacc[4];
  #pragma unroll
  for (int t=0;t<4;t++) gacc[t] = (f32x4)(0.f);
  {
    bf16x8 cah[2], cal[2];
    #pragma unroll
    for (int ks=0;ks<2;ks++){
      int ao = (w*16+l15)*72 + ks*32 + quad*8;
      cah[ks] = *(bf16x8*)&sCh[ao];
      cal[ks] = *(bf16x8*)&sCl[ao];
    }
    for (int bs=0; bs<=w; ++bs){
      #pragma unroll
      for (int ks=0;ks<2;ks++){
        int bo = (bs*16+l15)*72 + ks*32 + quad*8;
        bf16x8 bhf = *(bf16x8*)&sBh[bo];
        bf16x8 blf = *(bf16x8*)&sBl[bo];
        gacc[bs] = __builtin_amdgcn_mfma_f32_16x16x32_bf16(cah[ks], bhf, gacc[bs], 0,0,0);
        gacc[bs] = __builtin_amdgcn_mfma_f32_16x16x32_bf16(cah[ks], blf, gacc[bs], 0,0,0);
        gacc[bs] = __builtin_amdgcn_mfma_f32_16x16x32_bf16(cal[ks], bhf, gacc[bs], 0,0,0);
      }
    }
  }
  __syncthreads();   // sB reads done -> safe to overwrite with GM

  // ---- scale/mask, write GM bf16 hi/lo into sBh/sBl; zero needed tiles ----
  for (int bs=0; bs<=w; ++bs){
    #pragma unroll
    for (int r=0;r<4;r++){
      int i = w*16 + quad*4 + r;
      int s = bs*16 + l15;
      float v = 0.f;
      if (s <= i) v = gacc[bs][r] * __expf(sla[i]-sla[s]) * sdt[s];
      ushort_t hi = f2bf(v);
      sBh[i*72+s] = hi;
      sBl[i*72+s] = f2bf(v - bf2f(hi));
    }
  }
  if (w==0){
    #pragma unroll
    for (int r=0;r<4;r++){ sBh[(quad*4+r)*72 + 16+l15] = 0; sBl[(quad*4+r)*72 + 16+l15] = 0; }
  }
  if (w==2){
    #pragma unroll
    for (int r=0;r<4;r++){ sBh[(32+quad*4+r)*72 + 48+l15] = 0; sBl[(32+quad*4+r)*72 + 48+l15] = 0; }
  }
  __syncthreads();

  // ---- Sp fragments direct (pre-split, [p][n] layout) ----
  bf16x8 pah[3][2], pal[3][2];
  {
    const ushort_t* sph = Sp_h + (size_t)blk*3072;
    const ushort_t* spl = Sp_l + (size_t)blk*3072;
    #pragma unroll
    for (int pt=0;pt<3;pt++)
      #pragma unroll
      for (int ks=0;ks<2;ks++){
        size_t o = (size_t)(pt*16+l15)*64 + ks*32 + quad*8;
        pah[pt][ks] = *(const bf16x8*)(sph + o);
        pal[pt][ks] = *(const bf16x8*)(spl + o);
      }
  }

  // ---- O = X^T·GM^T (intra) ----
  f32x4 accI[3], accA[3];
  #pragma unroll
  for (int t=0;t<3;t++){ accI[t] = (f32x4)(0.f); accA[t] = (f32x4)(0.f); }
  int nks = (w>=2) ? 2 : 1;
  for (int ks=0; ks<nks; ++ks){
    int go = (w*16+l15)*72 + ks*32 + quad*8;
    bf16x8 gbh = *(bf16x8*)&sBh[go];
    bf16x8 gbl = *(bf16x8*)&sBl[go];
    #pragma unroll
    for (int pt=0;pt<3;pt++){
      int xo = (pt*16+l15)*72 + ks*32 + quad*8;
      bf16x8 xah = *(bf16x8*)&sXh[xo];
      bf16x8 xal = *(bf16x8*)&sXl[xo];
      accI[pt] = __builtin_amdgcn_mfma_f32_16x16x32_bf16(xah, gbh, accI[pt], 0,0,0);
      accI[pt] = __builtin_amdgcn_mfma_f32_16x16x32_bf16(xah, gbl, accI[pt], 0,0,0);
      accI[pt] = __builtin_amdgcn_mfma_f32_16x16x32_bf16(xal, gbh, accI[pt], 0,0,0);
    }
  }
  // ---- + Sp^T·C^T (carry) ----
  #pragma unroll
  for (int ks=0; ks<2; ++ks){
    int co = (w*16+l15)*72 + ks*32 + quad*8;
    bf16x8 cbh = *(bf16x8*)&sCh[co];
    bf16x8 cbl = *(bf16x8*)&sCl[co];
    #pragma unroll
    for (int pt=0;pt<3;pt++){
      accA[pt] = __builtin_amdgcn_mfma_f32_16x16x32_bf16(pah[pt][ks], cbh, accA[pt], 0,0,0);
      accA[pt] = __builtin_amdgcn_mfma_f32_16x16x32_bf16(pah[pt][ks], cbl, accA[pt], 0,0,0);
      accA[pt] = __builtin_amdgcn_mfma_f32_16x16x32_bf16(pal[pt][ks], cbh, accA[pt], 0,0,0);
    }
  }
  // ---- epilogue: Y[i][p] = accI + exp(la_i)*accA + D*x  -> bf16 ----
  {
    int i = w*16 + l15;
    float eli = __expf(sla[i]);
    float Dh = Dparam[hh];
    ushort_t* ybase = y16 + (size_t)(b*4096+t0+i)*384 + hh*48;
    #pragma unroll
    for (int pt=0;pt<3;pt++)
      #pragma unroll
      for (int r=0;r<4;r++){
        int p = pt*16 + quad*4 + r;
        float xf = bf2f(sXh[p*72 + i]) + bf2f(sXl[p*72 + i]);
        ybase[p] = f2bf(accI[pt][r] + eli*accA[pt][r] + Dh*xf);
      }
  }
}

// ----- gate: per-wave (1 token/wave), z from x (K=4), shuffle RMS; bf16 io -----
__global__ __launch_bounds__(256) void k_gate(
    const float* __restrict__ x, const float* __restrict__ Weff,
    const float* __restrict__ beff,
    const ushort_t* __restrict__ y16, ushort_t* __restrict__ yn16){
  int tid = threadIdx.x;
  int w = tid>>6, lane = tid&63;
  int e0 = lane*6;
  float W0[6],W1v[6],W2v[6],W3v[6],bv[6];
  #pragma unroll
  for (int c=0;c<6;c++){
    int e = e0+c;
    W0[c]=Weff[e]; W1v[c]=Weff[904+e]; W2v[c]=Weff[1808+e]; W3v[c]=Weff[2712+e];
    bv[c]=beff[e];
  }
  #pragma unroll
  for (int t=0;t<4;t++){
    int bl = blockIdx.x*16 + w*4 + t;
    float4 xv = *(const float4*)(x + (size_t)bl*4);
    float g[6]; float ss = 0.f;
    #pragma unroll
    for (int c=0;c<6;c++){
      float zv = bv[c];
      zv = fmaf(xv.x, W0[c], zv);
      zv = fmaf(xv.y, W1v[c], zv);
      zv = fmaf(xv.z, W2v[c], zv);
      zv = fmaf(xv.w, W3v[c], zv);
      float yv = bf2f(y16[(size_t)bl*384 + e0 + c]);
      float gg = yv * (zv * sigmoidf_(zv));
      g[c] = gg; ss += gg*gg;
    }
    #pragma unroll
    for (int off=32; off>0; off>>=1) ss += __shfl_xor(ss, off);
    float rms = rsqrtf(ss*(1.f/384.f) + 1e-5f);
    #pragma unroll
    for (int c=0;c<6;c++)
      yn16[(size_t)bl*384 + e0 + c] = f2bf(g[c]*rms);
  }
}

// ----- mlp2: 64 tokens/block, 2 tokens/thread; yn bf16 input -----
__global__ __launch_bounds__(256) void k_mlp2(
    const ushort_t* __restrict__ yn16, const float* __restrict__ Weff2,
    const float* __restrict__ b1, const float* __restrict__ W2,
    const float* __restrict__ b2, float* __restrict__ macc){
  __shared__ __align__(16) float sW[384][32];
  __shared__ __align__(16) float sm1[64][33];
  __shared__ __align__(16) float sW2[32][32];
  __shared__ __align__(16) float sm2[64][33];
  int tid = threadIdx.x;
  int tok0 = blockIdx.x*64;
  int b = tok0 >> 12;
  #pragma unroll
  for (int r=0;r<12;r++){
    int idx = tid + r*256;
    int row = idx>>3, c4 = (idx&7)*4;
    *(float4*)&sW[row][c4] = *(const float4*)(Weff2 + (size_t)idx*4);
  }
  {
    int row = tid>>3, c4 = (tid&7)*4;
    *(float4*)&sW2[row][c4] = *(const float4*)(W2 + row*32 + c4);
  }
  __syncthreads();
  {
    int tk = tid>>3, j0 = (tid&7)*4;
    float a0[4], a1[4];
    #pragma unroll
    for (int j=0;j<4;j++){ a0[j] = b1[j0+j]; a1[j] = a0[j]; }
    const ushort_t* y0 = yn16 + (size_t)(tok0+tk)*384;
    const ushort_t* y1 = yn16 + (size_t)(tok0+tk+32)*384;
    for (int k8=0;k8<48;k8++){
      ushort_t ua[8], ub[8];
      *(uint4*)ua = *(const uint4*)(y0 + k8*8);
      *(uint4*)ub = *(const uint4*)(y1 + k8*8);
      #pragma unroll
      for (int c=0;c<8;c++){
        float va = bf2f(ua[c]), vb = bf2f(ub[c]);
        float w[4]; *(float4*)w = *(float4*)&sW[k8*8+c][j0];
        #pragma unroll
        for (int j=0;j<4;j++){ a0[j] = fmaf(va, w[j], a0[j]); a1[j] = fmaf(vb, w[j], a1[j]); }
      }
    }
    #pragma unroll
    for (int j=0;j<4;j++){
      sm1[tk][j0+j]    = fmaxf(a0[j], 0.f);
      sm1[tk+32][j0+j] = fmaxf(a1[j], 0.f);
    }
  }
  __syncthreads();
  {
    int tk = tid>>3, j0 = (tid&7)*4;
    float a0[4], a1[4];
    #pragma unroll
    for (int j=0;j<4;j++){ a0[j] = b2[j0+j]; a1[j] = a0[j]; }
    #pragma unroll
    for (int kk=0;kk<32;kk++){
      float va = sm1[tk][kk];
      float vb = sm1[tk+32][kk];
      float w[4]; *(float4*)w = *(float4*)&sW2[kk][j0];
      #pragma unroll
      for (int j=0;j<4;j++){ a0[j] = fmaf(va, w[j], a0[j]); a1[j] = fmaf(vb, w[j], a1[j]); }
    }
    #pragma unroll
    for (int j=0;j<4;j++){
      sm2[tk][j0+j]    = fmaxf(a0[j], 0.f);
      sm2[tk+32][j0+j] = fmaxf(a1[j], 0.f);
    }
  }
  __syncthreads();
  if (tid < 32){
    float t = 0.f;
    #pragma unroll
    for (int tok=0;tok<64;tok++) t += sm2[tok][tid];
    atomicAdd(&macc[b*32 + tid], t);
  }
}

// ----- final: angle[b] = mean_m @ Wo + bo -----
__global__ void k_final(const float* __restrict__ macc, const float* __restrict__ Wo,
                        const float* __restrict__ bo, float* __restrict__ out){
  int tid = threadIdx.x;
  if (tid < 4){
    float acc = bo[0];
    #pragma unroll
    for (int j=0;j<32;j++) acc = fmaf(macc[tid*32+j]*(1.f/4096.f), Wo[j], acc);
    out[tid] = acc;
  }
}

// ---------------------------------------------------------------------------
extern "C" void kernel_launch(void* const* d_in, const int* in_sizes, int n_in,
                              void* d_out, int out_size, void* d_ws, size_t ws_size,
                              hipStream_t stream){
  const float* x      = (const float*)d_in[0];
  const float* Wfc    = (const float*)d_in[1];
  const float* bfc    = (const float*)d_in[2];
  const float* W_in   = (const float*)d_in[3];
  const float* conv_w = (const float*)d_in[4];
  const float* conv_b = (const float*)d_in[5];
  const float* dt_bias= (const float*)d_in[6];
  const float* A_log  = (const float*)d_in[7];
  const float* Dparam = (const float*)d_in[8];
  const float* norm_w = (const float*)d_in[9];
  const float* W_out  = (const float*)d_in[10];
  const float* W1     = (const float*)d_in[11];
  const float* b1     = (const float*)d_in[12];
  const float* W2     = (const float*)d_in[13];
  const float* b2     = (const float*)d_in[14];
  const float* Wo     = (const float*)d_in[15];
  const float* bo     = (const float*)d_in[16];
  float* ws  = (float*)d_ws;
  float* out = (float*)d_out;

  float* Weff  = ws + OFF_W;
  float* beff  = ws + OFF_W + 4096;
  float* Weff2 = ws + OFF_W + 8192;
  ushort_t* yn16 = (ushort_t*)(ws + OFF_Z);
  float* Tb    = ws + OFF_T;
  ushort_t* xs_h = (ushort_t*)(ws + OFF_XS);
  ushort_t* xs_l = xs_h + 6291456u;     // 32*4096*48
  ushort_t* Bm_h = (ushort_t*)(ws + OFF_BM);
  ushort_t* Bm_l = Bm_h + 1048576u;     // 16384*64
  ushort_t* Cm_h = (ushort_t*)(ws + OFF_CM);
  ushort_t* Cm_l = Cm_h + 1048576u;
  float* dtb   = ws + OFF_DT;
  float* lacb  = ws + OFF_LAC;
  ushort_t* Sp_h = (ushort_t*)(ws + OFF_SP);
  ushort_t* Sp_l = Sp_h + 6291456u;     // 2048*3072
  ushort_t* y16 = (ushort_t*)(ws + OFF_Y);
  float* macc  = ws + OFF_MACC;

  k_prep<<<dim3(52), dim3(256), 0, stream>>>(Wfc, bfc, W_in, W_out, W1, norm_w,
                                             Weff, beff, Weff2, macc);
  k_ipc<<<dim3(BL/2), dim3(256), 0, stream>>>(x, Weff, beff, conv_w, conv_b,
                                              dt_bias, xs_h, xs_l, Bm_h, Bm_l,
                                              Cm_h, Cm_l, dtb);
  k_phase1<<<dim3(BH*NC), dim3(256), 0, stream>>>(dtb, Bm_h, Bm_l, xs_h, xs_l,
                                                  A_log, Tb, lacb);
  k_phase2p<<<dim3(BH,48), dim3(256), 0, stream>>>(Tb, lacb, Sp_h, Sp_l);
  k_phase3<<<dim3(BH*NC), dim3(256), 0, stream>>>(dtb, lacb, Bm_h, Bm_l,
                                                  Cm_h, Cm_l, xs_h, xs_l,
                                                  Sp_h, Sp_l, Dparam, y16);
  k_gate<<<dim3(BL/16), dim3(256), 0, stream>>>(x, Weff, beff, y16, yn16);
  k_mlp2<<<dim3(BL/64), dim3(256), 0, stream>>>(yn16, Weff2, b1, W2, b2, macc);
  k_final<<<dim3(1), dim3(64), 0, stream>>>(macc, Wo, bo, out);
}

// Round 16
// 189.492 us; speedup vs baseline: 1.1406x; 1.0517x over previous
//
#include <hip/hip_runtime.h>
#include <math.h>

// ---------------------------------------------------------------------------
// MambaAnglePredictor — Round 16 (R15 +):
//   T, Sp, GM single bf16 (scan-internal tensors; dt/decay stay fp32)
//   phase3: intra/carry 2 MFMAs per tile (was 3)
//   ipc: 4 tokens/block
// ---------------------------------------------------------------------------

#define BDIM 4
#define LDIM 4096
#define BL (BDIM*LDIM)      // 16384 tokens
#define QC 64
#define NC (LDIM/QC)        // 64
#define BH (BDIM*NH)        // 32
#define NH 8

// workspace offsets (floats)
#define OFF_W    0u          // Weff 4x904 @0, beff @4096, Weff2 @8192
#define OFF_Z    3145728u    // yn bf16
#define OFF_T    9437184u    // T bf16 [p][n] per chunk
#define OFF_XS   17825792u   // xs_h | xs_l
#define OFF_BM   24117248u   // Bm_h | Bm_l
#define OFF_CM   25165824u   // Cm_h | Cm_l
#define OFF_DT   26214400u   // 32*4096 fp32
#define OFF_LAC  26345472u   // 2048*64 fp32
#define OFF_SP   26476544u   // Sp bf16 [p][n] per chunk
#define OFF_Y    32768000u   // y bf16
#define OFF_MACC 39059456u   // 4*32

typedef unsigned short ushort_t;
typedef __attribute__((ext_vector_type(8))) short bf16x8;
typedef __attribute__((ext_vector_type(4))) float f32x4;

__device__ __forceinline__ float sigmoidf_(float x){ return 1.0f/(1.0f+__expf(-x)); }
__device__ __forceinline__ ushort_t f2bf(float x){
  unsigned int u = __float_as_uint(x);
  u += 0x7fffu + ((u>>16)&1u);
  return (ushort_t)(u>>16);
}
__device__ __forceinline__ float bf2f(ushort_t h){
  return __uint_as_float(((unsigned int)h)<<16);
}

// ----- prep (merged): Weff, beff, Weff2 (nw-folded), macc zero -----
__global__ void k_prep(const float* __restrict__ Wfc, const float* __restrict__ bfc,
                       const float* __restrict__ W_in, const float* __restrict__ W_out,
                       const float* __restrict__ W1, const float* __restrict__ norm_w,
                       float* __restrict__ Weff, float* __restrict__ beff,
                       float* __restrict__ Weff2, float* __restrict__ macc){
  int blk = blockIdx.x, tid = threadIdx.x;
  if (blk < 4){
    int n = blk*256 + tid;
    if (n >= 904) return;
    float a0=0.f,a1=0.f,a2=0.f,a3=0.f,ab=0.f;
    for (int d=0; d<192; d++){
      float w = W_in[(size_t)d*904 + n];
      a0 = fmaf(Wfc[d], w, a0);
      a1 = fmaf(Wfc[192+d], w, a1);
      a2 = fmaf(Wfc[384+d], w, a2);
      a3 = fmaf(Wfc[576+d], w, a3);
      ab = fmaf(bfc[d], w, ab);
    }
    Weff[n] = a0; Weff[904+n] = a1; Weff[1808+n] = a2; Weff[2712+n] = a3;
    beff[n] = ab;
  } else {
    if (blk == 4 && tid < 128) macc[tid] = 0.f;
    int g = (blk-4)*256 + tid;
    int i = g>>5, j = g&31;
    float a = 0.f;
    for (int d=0; d<192; d++) a = fmaf(W_out[(size_t)i*192+d], W1[d*32+j], a);
    Weff2[g] = a * norm_w[i];
  }
}

// ----- ipc: fused in_proj+conv+silu+dt; 4 tokens/block, weights loaded once -----
__global__ __launch_bounds__(256) void k_ipc(
    const float* __restrict__ x, const float* __restrict__ Weff,
    const float* __restrict__ beff, const float* __restrict__ conv_w,
    const float* __restrict__ conv_b, const float* __restrict__ dt_bias,
    ushort_t* __restrict__ xs_h, ushort_t* __restrict__ xs_l,
    ushort_t* __restrict__ Bm_h, ushort_t* __restrict__ Bm_l,
    ushort_t* __restrict__ Cm_h, ushort_t* __restrict__ Cm_l,
    float* __restrict__ dtb){
  __shared__ float sx[7][4];            // x rows l0-3 .. l0+3
  int pb = blockIdx.x, tid = threadIdx.x;
  int bl0 = pb*4;
  int l0 = bl0 & 4095, b = bl0 >> 12;
  if (tid < 28){
    int row = tid>>2, r = tid&3;
    int ll = l0-3+row;
    sx[row][r] = (ll>=0) ? x[(size_t)(b*4096+ll)*4 + r] : 0.f;
  }
  __syncthreads();
  if (tid < 32){
    int t = tid>>3, hh = tid&7;
    float raw = beff[896+hh];
    #pragma unroll
    for (int r=0;r<4;r++) raw = fmaf(sx[3+t][r], Weff[r*904+896+hh], raw);
    float xx = raw + dt_bias[hh];
    float dtv = (xx > 20.f) ? xx : log1pf(__expf(xx));
    dtb[(size_t)(b*8+hh)*4096 + l0 + t] = dtv;
  }
  #pragma unroll
  for (int half=0; half<2; half++){
    int c = tid + half*256;
    float w0 = Weff[384+c];
    float w1 = Weff[904+384+c];
    float w2 = Weff[1808+384+c];
    float w3 = Weff[2712+384+c];
    float bb = beff[384+c];
    float cw0 = conv_w[c], cw1 = conv_w[512+c], cw2 = conv_w[1024+c], cw3 = conv_w[1536+c];
    float cb = conv_b[c];
    float pre[7];
    #pragma unroll
    for (int q=0;q<7;q++){
      int ll = l0-3+q;
      float xv = bb;
      xv = fmaf(sx[q][0], w0, xv);
      xv = fmaf(sx[q][1], w1, xv);
      xv = fmaf(sx[q][2], w2, xv);
      xv = fmaf(sx[q][3], w3, xv);
      pre[q] = (ll >= 0) ? xv : 0.f;
    }
    float av[4];
    #pragma unroll
    for (int t=0;t<4;t++){
      float a = cb;
      a = fmaf(cw0,pre[t+0],a); a = fmaf(cw1,pre[t+1],a);
      a = fmaf(cw2,pre[t+2],a); a = fmaf(cw3,pre[t+3],a);
      av[t] = a * sigmoidf_(a);
    }
    if (c < 384){
      int hh = c / 48, p = c - hh*48;
      size_t idx = (size_t)((b*8+hh)*4096 + l0)*48 + p;
      #pragma unroll
      for (int t=0;t<4;t++){
        ushort_t h = f2bf(av[t]);
        xs_h[idx + t*48] = h;
        xs_l[idx + t*48] = f2bf(av[t] - bf2f(h));
      }
    } else if (c < 448){
      size_t idx = (size_t)bl0*64 + (c-384);
      #pragma unroll
      for (int t=0;t<4;t++){
        ushort_t h = f2bf(av[t]);
        Bm_h[idx + t*64] = h;
        Bm_l[idx + t*64] = f2bf(av[t] - bf2f(h));
      }
    } else {
      size_t idx = (size_t)bl0*64 + (c-448);
      #pragma unroll
      for (int t=0;t<4;t++){
        ushort_t h = f2bf(av[t]);
        Cm_h[idx + t*64] = h;
        Cm_l[idx + t*64] = f2bf(av[t] - bf2f(h));
      }
    }
  }
}

// ----- phase1 (MFMA): T^T[p][n] = X^T · Bw per chunk; T emitted bf16 -----
__global__ __launch_bounds__(256, 3) void k_phase1(
    const float* __restrict__ dtbuf,
    const ushort_t* __restrict__ Bm_h, const ushort_t* __restrict__ Bm_l,
    const ushort_t* __restrict__ xs_h, const ushort_t* __restrict__ xs_l,
    const float* __restrict__ A_log,
    ushort_t* __restrict__ T, float* __restrict__ lac){
  __shared__ __align__(16) ushort_t sBh[64*72], sBl[64*72];   // Bw^T [n][s]
  __shared__ __align__(16) ushort_t sXh[48*72], sXl[48*72];   // X^T [p][s]
  __shared__ float sdt[64], sla[64], sw[64];
  int tid = threadIdx.x, blk = blockIdx.x;
  int bh = blk >> 6, k = blk & 63;
  int b = bh >> 3, hh = bh & 7;
  int t0 = k*64;
  int w = tid>>6, lane = tid&63, l15 = lane&15, quad = lane>>4;

  if (tid < 64) sdt[tid] = dtbuf[(size_t)bh*4096 + t0 + tid];
  __syncthreads();
  if (tid == 0){
    float eA = __expf(A_log[hh]);
    float cum = 0.f;
    for (int i=0;i<64;i++){ cum -= sdt[i]*eA; sla[i] = cum; }
  }
  __syncthreads();
  if (tid < 64){
    sw[tid] = __expf(sla[63]-sla[tid])*sdt[tid];
    lac[(size_t)blk*64 + tid] = sla[tid];
  }
  __syncthreads();
  // ---- stage Bw^T [n][s]: reconstruct, scale by sw, re-split ----
  {
    int s2 = (tid&31)*2, ng = (tid>>5)*8;
    size_t base0 = (size_t)(b*4096+t0+s2)*64 + ng;
    ushort_t h0a[8], l0a[8], h1a[8], l1a[8];
    *(uint4*)h0a = *(const uint4*)(Bm_h + base0);
    *(uint4*)l0a = *(const uint4*)(Bm_l + base0);
    *(uint4*)h1a = *(const uint4*)(Bm_h + base0 + 64);
    *(uint4*)l1a = *(const uint4*)(Bm_l + base0 + 64);
    float w0 = sw[s2], w1 = sw[s2+1];
    #pragma unroll
    for (int c=0;c<8;c++){
      float f0 = (bf2f(h0a[c]) + bf2f(l0a[c])) * w0;
      float f1 = (bf2f(h1a[c]) + bf2f(l1a[c])) * w1;
      ushort_t h0 = f2bf(f0), h1 = f2bf(f1);
      ushort_t lo0 = f2bf(f0-bf2f(h0)), lo1 = f2bf(f1-bf2f(h1));
      int o = (ng+c)*72 + s2;
      *(unsigned int*)&sBh[o] = (unsigned int)h0 | ((unsigned int)h1<<16);
      *(unsigned int*)&sBl[o] = (unsigned int)lo0 | ((unsigned int)lo1<<16);
    }
  }
  // ---- stage X^T [p][s]: pure copy + pack (pre-split) ----
  {
    int s2 = (tid>>3)*2, p0 = (tid&7)*6;
    const ushort_t* xh0 = xs_h + (size_t)(bh*4096+t0+s2)*48 + p0;
    const ushort_t* xl0 = xs_l + (size_t)(bh*4096+t0+s2)*48 + p0;
    #pragma unroll
    for (int c=0;c<6;c++){
      unsigned int hv = (unsigned int)xh0[c] | ((unsigned int)xh0[48+c]<<16);
      unsigned int lv = (unsigned int)xl0[c] | ((unsigned int)xl0[48+c]<<16);
      int o = (p0+c)*72 + s2;
      *(unsigned int*)&sXh[o] = hv;
      *(unsigned int*)&sXl[o] = lv;
    }
  }
  __syncthreads();
  f32x4 acc[3];
  #pragma unroll
  for (int t=0;t<3;t++) acc[t] = (f32x4)(0.f);
  #pragma unroll
  for (int ks=0;ks<2;ks++){
    int bo = (w*16+l15)*72 + ks*32 + quad*8;
    bf16x8 bbh = *(bf16x8*)&sBh[bo];
    bf16x8 bbl = *(bf16x8*)&sBl[bo];
    #pragma unroll
    for (int pt=0;pt<3;pt++){
      int xo = (pt*16+l15)*72 + ks*32 + quad*8;
      bf16x8 xah = *(bf16x8*)&sXh[xo];
      bf16x8 xal = *(bf16x8*)&sXl[xo];
      acc[pt] = __builtin_amdgcn_mfma_f32_16x16x32_bf16(xah, bbh, acc[pt], 0,0,0);
      acc[pt] = __builtin_amdgcn_mfma_f32_16x16x32_bf16(xah, bbl, acc[pt], 0,0,0);
      acc[pt] = __builtin_amdgcn_mfma_f32_16x16x32_bf16(xal, bbh, acc[pt], 0,0,0);
    }
  }
  {
    ushort_t* dst = T + (size_t)blk*3072;
    #pragma unroll
    for (int pt=0;pt<3;pt++)
      #pragma unroll
      for (int r=0;r<4;r++)
        dst[(pt*16+quad*4+r)*64 + w*16 + l15] = f2bf(acc[pt][r]);
  }
}

// ----- phase2p: Sp[k] = sum_{j<k} W[k][j] T[j]; T bf16 in, Sp bf16 out -----
__global__ __launch_bounds__(256) void k_phase2p(
    const ushort_t* __restrict__ T, const float* __restrict__ lac,
    ushort_t* __restrict__ Sp){
  __shared__ __align__(16) float sT[64*64];
  __shared__ __align__(16) float sW[64][68];
  __shared__ float sc[64];
  int tid = threadIdx.x;
  int bh = blockIdx.x, es = blockIdx.y;
  #pragma unroll
  for (int r=0;r<2;r++){
    int idx = tid + r*256;                 // 512 groups of 8
    int row = idx>>3, g8 = (idx&7)*8;
    ushort_t tv[8];
    *(uint4*)tv = *(const uint4*)(T + (size_t)(bh*64+row)*3072 + es*64 + g8);
    #pragma unroll
    for (int c=0;c<8;c++) sT[row*64 + g8 + c] = bf2f(tv[c]);
  }
  if (tid < 64) sc[tid] = __expf(lac[(size_t)(bh*64+tid)*64 + 63]);
  __syncthreads();
  if (tid < 64){
    int k = tid;
    float w = 1.f;
    for (int j=63; j>=0; --j){
      bool a = (j < k);
      sW[j][k] = a ? w : 0.f;
      if (a) w *= sc[j];
    }
  }
  __syncthreads();
  int k0 = (tid>>4)*4, e0 = (tid&15)*4;
  float acc[4][4];
  #pragma unroll
  for (int i=0;i<4;i++)
    #pragma unroll
    for (int j=0;j<4;j++) acc[i][j]=0.f;
  int jmax = k0+2; if (jmax > 62) jmax = 62;
  for (int j=0; j<=jmax; ++j){
    float wv[4], tv[4];
    *(float4*)wv = *(float4*)&sW[j][k0];
    *(float4*)tv = *(float4*)&sT[j*64 + e0];
    #pragma unroll
    for (int i=0;i<4;i++)
      #pragma unroll
      for (int e=0;e<4;e++) acc[i][e] = fmaf(wv[i], tv[e], acc[i][e]);
  }
  #pragma unroll
  for (int i=0;i<4;i++){
    ushort4 h4;
    ushort_t* hp = (ushort_t*)&h4;
    #pragma unroll
    for (int e=0;e<4;e++) hp[e] = f2bf(acc[i][e]);
    *(ushort4*)(Sp + (size_t)(bh*64+k0+i)*3072 + es*64 + e0) = h4;
  }
}

// ----- phase3 (MFMA): GM single bf16; carry/intra 2-term -----
__global__ __launch_bounds__(256, 3) void k_phase3(
    const float* __restrict__ dtbuf, const float* __restrict__ lac,
    const ushort_t* __restrict__ Bm_h, const ushort_t* __restrict__ Bm_l,
    const ushort_t* __restrict__ Cm_h, const ushort_t* __restrict__ Cm_l,
    const ushort_t* __restrict__ xs_h, const ushort_t* __restrict__ xs_l,
    const ushort_t* __restrict__ Sp, const float* __restrict__ Dparam,
    ushort_t* __restrict__ y16){
  __shared__ __align__(16) ushort_t sCh[64*72], sCl[64*72];   // C[i][n]
  __shared__ __align__(16) ushort_t sBh[64*72], sBl[64*72];   // B[s][n] -> GM[i][s] (sBh)
  __shared__ __align__(16) ushort_t sXh[48*72], sXl[48*72];   // X^T[p][s]
  __shared__ float sla[64], sdt[64];
  int tid = threadIdx.x, blk = blockIdx.x;
  int bh = blk>>6, k = blk&63, b = bh>>3, hh = bh&7, t0 = k*64;
  int w = tid>>6, lane = tid&63, l15 = lane&15, quad = lane>>4;

  if (tid < 64){
    sdt[tid] = dtbuf[(size_t)bh*4096 + t0 + tid];
    sla[tid] = lac[(size_t)blk*64 + tid];
  }
  // ---- stage C, B: pure 16B copies ----
  {
    int row = tid>>2, ng = (tid&3)*16;
    size_t gb = (size_t)(b*4096+t0+row)*64 + ng;
    int o = row*72 + ng;
    *(uint4*)&sCh[o]   = *(const uint4*)(Cm_h + gb);
    *(uint4*)&sCh[o+8] = *(const uint4*)(Cm_h + gb + 8);
    *(uint4*)&sCl[o]   = *(const uint4*)(Cm_l + gb);
    *(uint4*)&sCl[o+8] = *(const uint4*)(Cm_l + gb + 8);
    *(uint4*)&sBh[o]   = *(const uint4*)(Bm_h + gb);
    *(uint4*)&sBh[o+8] = *(const uint4*)(Bm_h + gb + 8);
    *(uint4*)&sBl[o]   = *(const uint4*)(Bm_l + gb);
    *(uint4*)&sBl[o+8] = *(const uint4*)(Bm_l + gb + 8);
  }
  // ---- stage X^T: copy + pack ----
  {
    int s2 = (tid>>3)*2, p0 = (tid&7)*6;
    const ushort_t* xh0 = xs_h + (size_t)(bh*4096+t0+s2)*48 + p0;
    const ushort_t* xl0 = xs_l + (size_t)(bh*4096+t0+s2)*48 + p0;
    #pragma unroll
    for (int c=0;c<6;c++){
      unsigned int hv = (unsigned int)xh0[c] | ((unsigned int)xh0[48+c]<<16);
      unsigned int lv = (unsigned int)xl0[c] | ((unsigned int)xl0[48+c]<<16);
      int o = (p0+c)*72 + s2;
      *(unsigned int*)&sXh[o] = hv;
      *(unsigned int*)&sXl[o] = lv;
    }
  }
  __syncthreads();

  // ---- GM mfma: wave w owns i-band w, s-tiles 0..w (3-term: full precision) ----
  f32x4 gacc[4];
  #pragma unroll
  for (int t=0;t<4;t++) gacc[t] = (f32x4)(0.f);
  {
    bf16x8 cah[2], cal[2];
    #pragma unroll
    for (int ks=0;ks<2;ks++){
      int ao = (w*16+l15)*72 + ks*32 + quad*8;
      cah[ks] = *(bf16x8*)&sCh[ao];
      cal[ks] = *(bf16x8*)&sCl[ao];
    }
    for (int bs=0; bs<=w; ++bs){
      #pragma unroll
      for (int ks=0;ks<2;ks++){
        int bo = (bs*16+l15)*72 + ks*32 + quad*8;
        bf16x8 bhf = *(bf16x8*)&sBh[bo];
        bf16x8 blf = *(bf16x8*)&sBl[bo];
        gacc[bs] = __builtin_amdgcn_mfma_f32_16x16x32_bf16(cah[ks], bhf, gacc[bs], 0,0,0);
        gacc[bs] = __builtin_amdgcn_mfma_f32_16x16x32_bf16(cah[ks], blf, gacc[bs], 0,0,0);
        gacc[bs] = __builtin_amdgcn_mfma_f32_16x16x32_bf16(cal[ks], bhf, gacc[bs], 0,0,0);
      }
    }
  }
  __syncthreads();   // sB reads done -> safe to overwrite with GM

  // ---- scale/mask, write GM single bf16 into sBh; zero needed tiles ----
  for (int bs=0; bs<=w; ++bs){
    #pragma unroll
    for (int r=0;r<4;r++){
      int i = w*16 + quad*4 + r;
      int s = bs*16 + l15;
      float v = 0.f;
      if (s <= i) v = gacc[bs][r] * __expf(sla[i]-sla[s]) * sdt[s];
      sBh[i*72+s] = f2bf(v);
    }
  }
  if (w==0){
    #pragma unroll
    for (int r=0;r<4;r++) sBh[(quad*4+r)*72 + 16+l15] = 0;
  }
  if (w==2){
    #pragma unroll
    for (int r=0;r<4;r++) sBh[(32+quad*4+r)*72 + 48+l15] = 0;
  }
  __syncthreads();

  // ---- Sp fragments direct (single bf16, [p][n] layout) ----
  bf16x8 pah[3][2];
  {
    const ushort_t* sph = Sp + (size_t)blk*3072;
    #pragma unroll
    for (int pt=0;pt<3;pt++)
      #pragma unroll
      for (int ks=0;ks<2;ks++)
        pah[pt][ks] = *(const bf16x8*)(sph + (size_t)(pt*16+l15)*64 + ks*32 + quad*8);
  }

  // ---- O = X^T·GM^T (intra; GM single, X split -> 2 terms) ----
  f32x4 accI[3], accA[3];
  #pragma unroll
  for (int t=0;t<3;t++){ accI[t] = (f32x4)(0.f); accA[t] = (f32x4)(0.f); }
  int nks = (w>=2) ? 2 : 1;
  for (int ks=0; ks<nks; ++ks){
    int go = (w*16+l15)*72 + ks*32 + quad*8;
    bf16x8 gbh = *(bf16x8*)&sBh[go];
    #pragma unroll
    for (int pt=0;pt<3;pt++){
      int xo = (pt*16+l15)*72 + ks*32 + quad*8;
      bf16x8 xah = *(bf16x8*)&sXh[xo];
      bf16x8 xal = *(bf16x8*)&sXl[xo];
      accI[pt] = __builtin_amdgcn_mfma_f32_16x16x32_bf16(xah, gbh, accI[pt], 0,0,0);
      accI[pt] = __builtin_amdgcn_mfma_f32_16x16x32_bf16(xal, gbh, accI[pt], 0,0,0);
    }
  }
  // ---- + Sp^T·C^T (carry; Sp single, C split -> 2 terms) ----
  #pragma unroll
  for (int ks=0; ks<2; ++ks){
    int co = (w*16+l15)*72 + ks*32 + quad*8;
    bf16x8 cbh = *(bf16x8*)&sCh[co];
    bf16x8 cbl = *(bf16x8*)&sCl[co];
    #pragma unroll
    for (int pt=0;pt<3;pt++){
      accA[pt] = __builtin_amdgcn_mfma_f32_16x16x32_bf16(pah[pt][ks], cbh, accA[pt], 0,0,0);
      accA[pt] = __builtin_amdgcn_mfma_f32_16x16x32_bf16(pah[pt][ks], cbl, accA[pt], 0,0,0);
    }
  }
  // ---- epilogue: Y[i][p] = accI + exp(la_i)*accA + D*x  -> bf16 ----
  {
    int i = w*16 + l15;
    float eli = __expf(sla[i]);
    float Dh = Dparam[hh];
    ushort_t* ybase = y16 + (size_t)(b*4096+t0+i)*384 + hh*48;
    #pragma unroll
    for (int pt=0;pt<3;pt++)
      #pragma unroll
      for (int r=0;r<4;r++){
        int p = pt*16 + quad*4 + r;
        float xf = bf2f(sXh[p*72 + i]) + bf2f(sXl[p*72 + i]);
        ybase[p] = f2bf(accI[pt][r] + eli*accA[pt][r] + Dh*xf);
      }
  }
}

// ----- gate: per-wave (1 token/wave), z from x (K=4), shuffle RMS; bf16 io -----
__global__ __launch_bounds__(256) void k_gate(
    const float* __restrict__ x, const float* __restrict__ Weff,
    const float* __restrict__ beff,
    const ushort_t* __restrict__ y16, ushort_t* __restrict__ yn16){
  int tid = threadIdx.x;
  int w = tid>>6, lane = tid&63;
  int e0 = lane*6;
  float W0[6],W1v[6],W2v[6],W3v[6],bv[6];
  #pragma unroll
  for (int c=0;c<6;c++){
    int e = e0+c;
    W0[c]=Weff[e]; W1v[c]=Weff[904+e]; W2v[c]=Weff[1808+e]; W3v[c]=Weff[2712+e];
    bv[c]=beff[e];
  }
  #pragma unroll
  for (int t=0;t<4;t++){
    int bl = blockIdx.x*16 + w*4 + t;
    float4 xv = *(const float4*)(x + (size_t)bl*4);
    float g[6]; float ss = 0.f;
    #pragma unroll
    for (int c=0;c<6;c++){
      float zv = bv[c];
      zv = fmaf(xv.x, W0[c], zv);
      zv = fmaf(xv.y, W1v[c], zv);
      zv = fmaf(xv.z, W2v[c], zv);
      zv = fmaf(xv.w, W3v[c], zv);
      float yv = bf2f(y16[(size_t)bl*384 + e0 + c]);
      float gg = yv * (zv * sigmoidf_(zv));
      g[c] = gg; ss += gg*gg;
    }
    #pragma unroll
    for (int off=32; off>0; off>>=1) ss += __shfl_xor(ss, off);
    float rms = rsqrtf(ss*(1.f/384.f) + 1e-5f);
    #pragma unroll
    for (int c=0;c<6;c++)
      yn16[(size_t)bl*384 + e0 + c] = f2bf(g[c]*rms);
  }
}

// ----- mlp2: 64 tokens/block, 2 tokens/thread; yn bf16 input -----
__global__ __launch_bounds__(256) void k_mlp2(
    const ushort_t* __restrict__ yn16, const float* __restrict__ Weff2,
    const float* __restrict__ b1, const float* __restrict__ W2,
    const float* __restrict__ b2, float* __restrict__ macc){
  __shared__ __align__(16) float sW[384][32];
  __shared__ __align__(16) float sm1[64][33];
  __shared__ __align__(16) float sW2[32][32];
  __shared__ __align__(16) float sm2[64][33];
  int tid = threadIdx.x;
  int tok0 = blockIdx.x*64;
  int b = tok0 >> 12;
  #pragma unroll
  for (int r=0;r<12;r++){
    int idx = tid + r*256;
    int row = idx>>3, c4 = (idx&7)*4;
    *(float4*)&sW[row][c4] = *(const float4*)(Weff2 + (size_t)idx*4);
  }
  {
    int row = tid>>3, c4 = (tid&7)*4;
    *(float4*)&sW2[row][c4] = *(const float4*)(W2 + row*32 + c4);
  }
  __syncthreads();
  {
    int tk = tid>>3, j0 = (tid&7)*4;
    float a0[4], a1[4];
    #pragma unroll
    for (int j=0;j<4;j++){ a0[j] = b1[j0+j]; a1[j] = a0[j]; }
    const ushort_t* y0 = yn16 + (size_t)(tok0+tk)*384;
    const ushort_t* y1 = yn16 + (size_t)(tok0+tk+32)*384;
    for (int k8=0;k8<48;k8++){
      ushort_t ua[8], ub[8];
      *(uint4*)ua = *(const uint4*)(y0 + k8*8);
      *(uint4*)ub = *(const uint4*)(y1 + k8*8);
      #pragma unroll
      for (int c=0;c<8;c++){
        float va = bf2f(ua[c]), vb = bf2f(ub[c]);
        float w[4]; *(float4*)w = *(float4*)&sW[k8*8+c][j0];
        #pragma unroll
        for (int j=0;j<4;j++){ a0[j] = fmaf(va, w[j], a0[j]); a1[j] = fmaf(vb, w[j], a1[j]); }
      }
    }
    #pragma unroll
    for (int j=0;j<4;j++){
      sm1[tk][j0+j]    = fmaxf(a0[j], 0.f);
      sm1[tk+32][j0+j] = fmaxf(a1[j], 0.f);
    }
  }
  __syncthreads();
  {
    int tk = tid>>3, j0 = (tid&7)*4;
    float a0[4], a1[4];
    #pragma unroll
    for (int j=0;j<4;j++){ a0[j] = b2[j0+j]; a1[j] = a0[j]; }
    #pragma unroll
    for (int kk=0;kk<32;kk++){
      float va = sm1[tk][kk];
      float vb = sm1[tk+32][kk];
      float w[4]; *(float4*)w = *(float4*)&sW2[kk][j0];
      #pragma unroll
      for (int j=0;j<4;j++){ a0[j] = fmaf(va, w[j], a0[j]); a1[j] = fmaf(vb, w[j], a1[j]); }
    }
    #pragma unroll
    for (int j=0;j<4;j++){
      sm2[tk][j0+j]    = fmaxf(a0[j], 0.f);
      sm2[tk+32][j0+j] = fmaxf(a1[j], 0.f);
    }
  }
  __syncthreads();
  if (tid < 32){
    float t = 0.f;
    #pragma unroll
    for (int tok=0;tok<64;tok++) t += sm2[tok][tid];
    atomicAdd(&macc[b*32 + tid], t);
  }
}

// ----- final: angle[b] = mean_m @ Wo + bo -----
__global__ void k_final(const float* __restrict__ macc, const float* __restrict__ Wo,
                        const float* __restrict__ bo, float* __restrict__ out){
  int tid = threadIdx.x;
  if (tid < 4){
    float acc = bo[0];
    #pragma unroll
    for (int j=0;j<32;j++) acc = fmaf(macc[tid*32+j]*(1.f/4096.f), Wo[j], acc);
    out[tid] = acc;
  }
}

// ---------------------------------------------------------------------------
extern "C" void kernel_launch(void* const* d_in, const int* in_sizes, int n_in,
                              void* d_out, int out_size, void* d_ws, size_t ws_size,
                              hipStream_t stream){
  const float* x      = (const float*)d_in[0];
  const float* Wfc    = (const float*)d_in[1];
  const float* bfc    = (const float*)d_in[2];
  const float* W_in   = (const float*)d_in[3];
  const float* conv_w = (const float*)d_in[4];
  const float* conv_b = (const float*)d_in[5];
  const float* dt_bias= (const float*)d_in[6];
  const float* A_log  = (const float*)d_in[7];
  const float* Dparam = (const float*)d_in[8];
  const float* norm_w = (const float*)d_in[9];
  const float* W_out  = (const float*)d_in[10];
  const float* W1     = (const float*)d_in[11];
  const float* b1     = (const float*)d_in[12];
  const float* W2     = (const float*)d_in[13];
  const float* b2     = (const float*)d_in[14];
  const float* Wo     = (const float*)d_in[15];
  const float* bo     = (const float*)d_in[16];
  float* ws  = (float*)d_ws;
  float* out = (float*)d_out;

  float* Weff  = ws + OFF_W;
  float* beff  = ws + OFF_W + 4096;
  float* Weff2 = ws + OFF_W + 8192;
  ushort_t* yn16 = (ushort_t*)(ws + OFF_Z);
  ushort_t* Tb   = (ushort_t*)(ws + OFF_T);
  ushort_t* xs_h = (ushort_t*)(ws + OFF_XS);
  ushort_t* xs_l = xs_h + 6291456u;     // 32*4096*48
  ushort_t* Bm_h = (ushort_t*)(ws + OFF_BM);
  ushort_t* Bm_l = Bm_h + 1048576u;     // 16384*64
  ushort_t* Cm_h = (ushort_t*)(ws + OFF_CM);
  ushort_t* Cm_l = Cm_h + 1048576u;
  float* dtb   = ws + OFF_DT;
  float* lacb  = ws + OFF_LAC;
  ushort_t* Spb  = (ushort_t*)(ws + OFF_SP);
  ushort_t* y16 = (ushort_t*)(ws + OFF_Y);
  float* macc  = ws + OFF_MACC;

  k_prep<<<dim3(52), dim3(256), 0, stream>>>(Wfc, bfc, W_in, W_out, W1, norm_w,
                                             Weff, beff, Weff2, macc);
  k_ipc<<<dim3(BL/4), dim3(256), 0, stream>>>(x, Weff, beff, conv_w, conv_b,
                                              dt_bias, xs_h, xs_l, Bm_h, Bm_l,
                                              Cm_h, Cm_l, dtb);
  k_phase1<<<dim3(BH*NC), dim3(256), 0, stream>>>(dtb, Bm_h, Bm_l, xs_h, xs_l,
                                                  A_log, Tb, lacb);
  k_phase2p<<<dim3(BH,48), dim3(256), 0, stream>>>(Tb, lacb, Spb);
  k_phase3<<<dim3(BH*NC), dim3(256), 0, stream>>>(dtb, lacb, Bm_h, Bm_l,
                                                  Cm_h, Cm_l, xs_h, xs_l,
                                                  Spb, Dparam, y16);
  k_gate<<<dim3(BL/16), dim3(256), 0, stream>>>(x, Weff, beff, y16, yn16);
  k_mlp2<<<dim3(BL/64), dim3(256), 0, stream>>>(yn16, Weff2, b1, W2, b2, macc);
  k_final<<<dim3(1), dim3(64), 0, stream>>>(macc, Wo, bo, out);
}

// Round 17
// 186.069 us; speedup vs baseline: 1.1616x; 1.0184x over previous
//
#include <hip/hip_runtime.h>
#include <math.h>

// ---------------------------------------------------------------------------
// MambaAnglePredictor — Round 17 (R16 +):
//   gate fused into phase3 epilogue: g=y*silu(z) written bf16, per-token
//   sum(g^2) via quad-shuffle + atomicAdd(ssum); mlp2 applies rms inline.
//   k_gate eliminated (-1 dispatch, -25 MB HBM round-trip).
// ---------------------------------------------------------------------------

#define BDIM 4
#define LDIM 4096
#define BL (BDIM*LDIM)      // 16384 tokens
#define QC 64
#define NC (LDIM/QC)        // 64
#define BH (BDIM*NH)        // 32
#define NH 8

// workspace offsets (floats)
#define OFF_W    0u          // Weff 4x904 @0, beff @4096, Weff2 @8192
#define OFF_Z    3145728u    // ssum fp32 [16384]
#define OFF_T    9437184u    // T bf16 [p][n] per chunk
#define OFF_XS   17825792u   // xs_h | xs_l
#define OFF_BM   24117248u   // Bm_h | Bm_l
#define OFF_CM   25165824u   // Cm_h | Cm_l
#define OFF_DT   26214400u   // 32*4096 fp32
#define OFF_LAC  26345472u   // 2048*64 fp32
#define OFF_SP   26476544u   // Sp bf16 [p][n] per chunk
#define OFF_Y    32768000u   // g bf16 (gated y, pre-RMS)
#define OFF_MACC 39059456u   // 4*32

typedef unsigned short ushort_t;
typedef __attribute__((ext_vector_type(8))) short bf16x8;
typedef __attribute__((ext_vector_type(4))) float f32x4;

__device__ __forceinline__ float sigmoidf_(float x){ return 1.0f/(1.0f+__expf(-x)); }
__device__ __forceinline__ ushort_t f2bf(float x){
  unsigned int u = __float_as_uint(x);
  u += 0x7fffu + ((u>>16)&1u);
  return (ushort_t)(u>>16);
}
__device__ __forceinline__ float bf2f(ushort_t h){
  return __uint_as_float(((unsigned int)h)<<16);
}

// ----- prep (merged): Weff, beff, Weff2 (nw-folded), macc zero, ssum zero -----
__global__ void k_prep(const float* __restrict__ Wfc, const float* __restrict__ bfc,
                       const float* __restrict__ W_in, const float* __restrict__ W_out,
                       const float* __restrict__ W1, const float* __restrict__ norm_w,
                       float* __restrict__ Weff, float* __restrict__ beff,
                       float* __restrict__ Weff2, float* __restrict__ macc,
                       float* __restrict__ ssum){
  int blk = blockIdx.x, tid = threadIdx.x;
  if (blk < 4){
    int n = blk*256 + tid;
    if (n >= 904) return;
    float a0=0.f,a1=0.f,a2=0.f,a3=0.f,ab=0.f;
    for (int d=0; d<192; d++){
      float w = W_in[(size_t)d*904 + n];
      a0 = fmaf(Wfc[d], w, a0);
      a1 = fmaf(Wfc[192+d], w, a1);
      a2 = fmaf(Wfc[384+d], w, a2);
      a3 = fmaf(Wfc[576+d], w, a3);
      ab = fmaf(bfc[d], w, ab);
    }
    Weff[n] = a0; Weff[904+n] = a1; Weff[1808+n] = a2; Weff[2712+n] = a3;
    beff[n] = ab;
  } else if (blk < 52){
    if (blk == 4 && tid < 128) macc[tid] = 0.f;
    int g = (blk-4)*256 + tid;
    int i = g>>5, j = g&31;
    float a = 0.f;
    for (int d=0; d<192; d++) a = fmaf(W_out[(size_t)i*192+d], W1[d*32+j], a);
    Weff2[g] = a * norm_w[i];
  } else {
    int idx = (blk-52)*256 + tid;       // 64 blocks * 256 = 16384
    ssum[idx] = 0.f;
  }
}

// ----- ipc: fused in_proj+conv+silu+dt; 4 tokens/block, weights loaded once -----
__global__ __launch_bounds__(256) void k_ipc(
    const float* __restrict__ x, const float* __restrict__ Weff,
    const float* __restrict__ beff, const float* __restrict__ conv_w,
    const float* __restrict__ conv_b, const float* __restrict__ dt_bias,
    ushort_t* __restrict__ xs_h, ushort_t* __restrict__ xs_l,
    ushort_t* __restrict__ Bm_h, ushort_t* __restrict__ Bm_l,
    ushort_t* __restrict__ Cm_h, ushort_t* __restrict__ Cm_l,
    float* __restrict__ dtb){
  __shared__ float sx[7][4];            // x rows l0-3 .. l0+3
  int pb = blockIdx.x, tid = threadIdx.x;
  int bl0 = pb*4;
  int l0 = bl0 & 4095, b = bl0 >> 12;
  if (tid < 28){
    int row = tid>>2, r = tid&3;
    int ll = l0-3+row;
    sx[row][r] = (ll>=0) ? x[(size_t)(b*4096+ll)*4 + r] : 0.f;
  }
  __syncthreads();
  if (tid < 32){
    int t = tid>>3, hh = tid&7;
    float raw = beff[896+hh];
    #pragma unroll
    for (int r=0;r<4;r++) raw = fmaf(sx[3+t][r], Weff[r*904+896+hh], raw);
    float xx = raw + dt_bias[hh];
    float dtv = (xx > 20.f) ? xx : log1pf(__expf(xx));
    dtb[(size_t)(b*8+hh)*4096 + l0 + t] = dtv;
  }
  #pragma unroll
  for (int half=0; half<2; half++){
    int c = tid + half*256;
    float w0 = Weff[384+c];
    float w1 = Weff[904+384+c];
    float w2 = Weff[1808+384+c];
    float w3 = Weff[2712+384+c];
    float bb = beff[384+c];
    float cw0 = conv_w[c], cw1 = conv_w[512+c], cw2 = conv_w[1024+c], cw3 = conv_w[1536+c];
    float cb = conv_b[c];
    float pre[7];
    #pragma unroll
    for (int q=0;q<7;q++){
      int ll = l0-3+q;
      float xv = bb;
      xv = fmaf(sx[q][0], w0, xv);
      xv = fmaf(sx[q][1], w1, xv);
      xv = fmaf(sx[q][2], w2, xv);
      xv = fmaf(sx[q][3], w3, xv);
      pre[q] = (ll >= 0) ? xv : 0.f;
    }
    float av[4];
    #pragma unroll
    for (int t=0;t<4;t++){
      float a = cb;
      a = fmaf(cw0,pre[t+0],a); a = fmaf(cw1,pre[t+1],a);
      a = fmaf(cw2,pre[t+2],a); a = fmaf(cw3,pre[t+3],a);
      av[t] = a * sigmoidf_(a);
    }
    if (c < 384){
      int hh = c / 48, p = c - hh*48;
      size_t idx = (size_t)((b*8+hh)*4096 + l0)*48 + p;
      #pragma unroll
      for (int t=0;t<4;t++){
        ushort_t h = f2bf(av[t]);
        xs_h[idx + t*48] = h;
        xs_l[idx + t*48] = f2bf(av[t] - bf2f(h));
      }
    } else if (c < 448){
      size_t idx = (size_t)bl0*64 + (c-384);
      #pragma unroll
      for (int t=0;t<4;t++){
        ushort_t h = f2bf(av[t]);
        Bm_h[idx + t*64] = h;
        Bm_l[idx + t*64] = f2bf(av[t] - bf2f(h));
      }
    } else {
      size_t idx = (size_t)bl0*64 + (c-448);
      #pragma unroll
      for (int t=0;t<4;t++){
        ushort_t h = f2bf(av[t]);
        Cm_h[idx + t*64] = h;
        Cm_l[idx + t*64] = f2bf(av[t] - bf2f(h));
      }
    }
  }
}

// ----- phase1 (MFMA): T^T[p][n] = X^T · Bw per chunk; T emitted bf16 -----
__global__ __launch_bounds__(256, 3) void k_phase1(
    const float* __restrict__ dtbuf,
    const ushort_t* __restrict__ Bm_h, const ushort_t* __restrict__ Bm_l,
    const ushort_t* __restrict__ xs_h, const ushort_t* __restrict__ xs_l,
    const float* __restrict__ A_log,
    ushort_t* __restrict__ T, float* __restrict__ lac){
  __shared__ __align__(16) ushort_t sBh[64*72], sBl[64*72];   // Bw^T [n][s]
  __shared__ __align__(16) ushort_t sXh[48*72], sXl[48*72];   // X^T [p][s]
  __shared__ float sdt[64], sla[64], sw[64];
  int tid = threadIdx.x, blk = blockIdx.x;
  int bh = blk >> 6, k = blk & 63;
  int b = bh >> 3, hh = bh & 7;
  int t0 = k*64;
  int w = tid>>6, lane = tid&63, l15 = lane&15, quad = lane>>4;

  if (tid < 64) sdt[tid] = dtbuf[(size_t)bh*4096 + t0 + tid];
  __syncthreads();
  if (tid == 0){
    float eA = __expf(A_log[hh]);
    float cum = 0.f;
    for (int i=0;i<64;i++){ cum -= sdt[i]*eA; sla[i] = cum; }
  }
  __syncthreads();
  if (tid < 64){
    sw[tid] = __expf(sla[63]-sla[tid])*sdt[tid];
    lac[(size_t)blk*64 + tid] = sla[tid];
  }
  __syncthreads();
  // ---- stage Bw^T [n][s]: reconstruct, scale by sw, re-split ----
  {
    int s2 = (tid&31)*2, ng = (tid>>5)*8;
    size_t base0 = (size_t)(b*4096+t0+s2)*64 + ng;
    ushort_t h0a[8], l0a[8], h1a[8], l1a[8];
    *(uint4*)h0a = *(const uint4*)(Bm_h + base0);
    *(uint4*)l0a = *(const uint4*)(Bm_l + base0);
    *(uint4*)h1a = *(const uint4*)(Bm_h + base0 + 64);
    *(uint4*)l1a = *(const uint4*)(Bm_l + base0 + 64);
    float w0 = sw[s2], w1 = sw[s2+1];
    #pragma unroll
    for (int c=0;c<8;c++){
      float f0 = (bf2f(h0a[c]) + bf2f(l0a[c])) * w0;
      float f1 = (bf2f(h1a[c]) + bf2f(l1a[c])) * w1;
      ushort_t h0 = f2bf(f0), h1 = f2bf(f1);
      ushort_t lo0 = f2bf(f0-bf2f(h0)), lo1 = f2bf(f1-bf2f(h1));
      int o = (ng+c)*72 + s2;
      *(unsigned int*)&sBh[o] = (unsigned int)h0 | ((unsigned int)h1<<16);
      *(unsigned int*)&sBl[o] = (unsigned int)lo0 | ((unsigned int)lo1<<16);
    }
  }
  // ---- stage X^T [p][s]: pure copy + pack (pre-split) ----
  {
    int s2 = (tid>>3)*2, p0 = (tid&7)*6;
    const ushort_t* xh0 = xs_h + (size_t)(bh*4096+t0+s2)*48 + p0;
    const ushort_t* xl0 = xs_l + (size_t)(bh*4096+t0+s2)*48 + p0;
    #pragma unroll
    for (int c=0;c<6;c++){
      unsigned int hv = (unsigned int)xh0[c] | ((unsigned int)xh0[48+c]<<16);
      unsigned int lv = (unsigned int)xl0[c] | ((unsigned int)xl0[48+c]<<16);
      int o = (p0+c)*72 + s2;
      *(unsigned int*)&sXh[o] = hv;
      *(unsigned int*)&sXl[o] = lv;
    }
  }
  __syncthreads();
  f32x4 acc[3];
  #pragma unroll
  for (int t=0;t<3;t++) acc[t] = (f32x4)(0.f);
  #pragma unroll
  for (int ks=0;ks<2;ks++){
    int bo = (w*16+l15)*72 + ks*32 + quad*8;
    bf16x8 bbh = *(bf16x8*)&sBh[bo];
    bf16x8 bbl = *(bf16x8*)&sBl[bo];
    #pragma unroll
    for (int pt=0;pt<3;pt++){
      int xo = (pt*16+l15)*72 + ks*32 + quad*8;
      bf16x8 xah = *(bf16x8*)&sXh[xo];
      bf16x8 xal = *(bf16x8*)&sXl[xo];
      acc[pt] = __builtin_amdgcn_mfma_f32_16x16x32_bf16(xah, bbh, acc[pt], 0,0,0);
      acc[pt] = __builtin_amdgcn_mfma_f32_16x16x32_bf16(xah, bbl, acc[pt], 0,0,0);
      acc[pt] = __builtin_amdgcn_mfma_f32_16x16x32_bf16(xal, bbh, acc[pt], 0,0,0);
    }
  }
  {
    ushort_t* dst = T + (size_t)blk*3072;
    #pragma unroll
    for (int pt=0;pt<3;pt++)
      #pragma unroll
      for (int r=0;r<4;r++)
        dst[(pt*16+quad*4+r)*64 + w*16 + l15] = f2bf(acc[pt][r]);
  }
}

// ----- phase2p: Sp[k] = sum_{j<k} W[k][j] T[j]; T bf16 in, Sp bf16 out -----
__global__ __launch_bounds__(256) void k_phase2p(
    const ushort_t* __restrict__ T, const float* __restrict__ lac,
    ushort_t* __restrict__ Sp){
  __shared__ __align__(16) float sT[64*64];
  __shared__ __align__(16) float sW[64][68];
  __shared__ float sc[64];
  int tid = threadIdx.x;
  int bh = blockIdx.x, es = blockIdx.y;
  #pragma unroll
  for (int r=0;r<2;r++){
    int idx = tid + r*256;
    int row = idx>>3, g8 = (idx&7)*8;
    ushort_t tv[8];
    *(uint4*)tv = *(const uint4*)(T + (size_t)(bh*64+row)*3072 + es*64 + g8);
    #pragma unroll
    for (int c=0;c<8;c++) sT[row*64 + g8 + c] = bf2f(tv[c]);
  }
  if (tid < 64) sc[tid] = __expf(lac[(size_t)(bh*64+tid)*64 + 63]);
  __syncthreads();
  if (tid < 64){
    int k = tid;
    float w = 1.f;
    for (int j=63; j>=0; --j){
      bool a = (j < k);
      sW[j][k] = a ? w : 0.f;
      if (a) w *= sc[j];
    }
  }
  __syncthreads();
  int k0 = (tid>>4)*4, e0 = (tid&15)*4;
  float acc[4][4];
  #pragma unroll
  for (int i=0;i<4;i++)
    #pragma unroll
    for (int j=0;j<4;j++) acc[i][j]=0.f;
  int jmax = k0+2; if (jmax > 62) jmax = 62;
  for (int j=0; j<=jmax; ++j){
    float wv[4], tv[4];
    *(float4*)wv = *(float4*)&sW[j][k0];
    *(float4*)tv = *(float4*)&sT[j*64 + e0];
    #pragma unroll
    for (int i=0;i<4;i++)
      #pragma unroll
      for (int e=0;e<4;e++) acc[i][e] = fmaf(wv[i], tv[e], acc[i][e]);
  }
  #pragma unroll
  for (int i=0;i<4;i++){
    ushort4 h4;
    ushort_t* hp = (ushort_t*)&h4;
    #pragma unroll
    for (int e=0;e<4;e++) hp[e] = f2bf(acc[i][e]);
    *(ushort4*)(Sp + (size_t)(bh*64+k0+i)*3072 + es*64 + e0) = h4;
  }
}

// ----- phase3 (MFMA) + fused gate: GM single bf16; epilogue computes
//   g = y*silu(z(x)), writes g bf16, atomically accumulates sum(g^2)/token.
__global__ __launch_bounds__(256, 3) void k_phase3(
    const float* __restrict__ dtbuf, const float* __restrict__ lac,
    const ushort_t* __restrict__ Bm_h, const ushort_t* __restrict__ Bm_l,
    const ushort_t* __restrict__ Cm_h, const ushort_t* __restrict__ Cm_l,
    const ushort_t* __restrict__ xs_h, const ushort_t* __restrict__ xs_l,
    const ushort_t* __restrict__ Sp, const float* __restrict__ Dparam,
    const float* __restrict__ xg, const float* __restrict__ Weff,
    const float* __restrict__ beff,
    ushort_t* __restrict__ g16, float* __restrict__ ssum){
  __shared__ __align__(16) ushort_t sCh[64*72], sCl[64*72];   // C[i][n]
  __shared__ __align__(16) ushort_t sBh[64*72], sBl[64*72];   // B[s][n] -> GM[i][s]
  __shared__ __align__(16) ushort_t sXh[48*72], sXl[48*72];   // X^T[p][s]
  __shared__ float sla[64], sdt[64];
  int tid = threadIdx.x, blk = blockIdx.x;
  int bh = blk>>6, k = blk&63, b = bh>>3, hh = bh&7, t0 = k*64;
  int w = tid>>6, lane = tid&63, l15 = lane&15, quad = lane>>4;

  if (tid < 64){
    sdt[tid] = dtbuf[(size_t)bh*4096 + t0 + tid];
    sla[tid] = lac[(size_t)blk*64 + tid];
  }
  // ---- stage C, B: pure 16B copies ----
  {
    int row = tid>>2, ng = (tid&3)*16;
    size_t gb = (size_t)(b*4096+t0+row)*64 + ng;
    int o = row*72 + ng;
    *(uint4*)&sCh[o]   = *(const uint4*)(Cm_h + gb);
    *(uint4*)&sCh[o+8] = *(const uint4*)(Cm_h + gb + 8);
    *(uint4*)&sCl[o]   = *(const uint4*)(Cm_l + gb);
    *(uint4*)&sCl[o+8] = *(const uint4*)(Cm_l + gb + 8);
    *(uint4*)&sBh[o]   = *(const uint4*)(Bm_h + gb);
    *(uint4*)&sBh[o+8] = *(const uint4*)(Bm_h + gb + 8);
    *(uint4*)&sBl[o]   = *(const uint4*)(Bm_l + gb);
    *(uint4*)&sBl[o+8] = *(const uint4*)(Bm_l + gb + 8);
  }
  // ---- stage X^T: copy + pack ----
  {
    int s2 = (tid>>3)*2, p0 = (tid&7)*6;
    const ushort_t* xh0 = xs_h + (size_t)(bh*4096+t0+s2)*48 + p0;
    const ushort_t* xl0 = xs_l + (size_t)(bh*4096+t0+s2)*48 + p0;
    #pragma unroll
    for (int c=0;c<6;c++){
      unsigned int hv = (unsigned int)xh0[c] | ((unsigned int)xh0[48+c]<<16);
      unsigned int lv = (unsigned int)xl0[c] | ((unsigned int)xl0[48+c]<<16);
      int o = (p0+c)*72 + s2;
      *(unsigned int*)&sXh[o] = hv;
      *(unsigned int*)&sXl[o] = lv;
    }
  }
  __syncthreads();

  // ---- GM mfma: wave w owns i-band w, s-tiles 0..w (3-term split) ----
  f32x4 gacc[4];
  #pragma unroll
  for (int t=0;t<4;t++) gacc[t] = (f32x4)(0.f);
  {
    bf16x8 cah[2], cal[2];
    #pragma unroll
    for (int ks=0;ks<2;ks++){
      int ao = (w*16+l15)*72 + ks*32 + quad*8;
      cah[ks] = *(bf16x8*)&sCh[ao];
      cal[ks] = *(bf16x8*)&sCl[ao];
    }
    for (int bs=0; bs<=w; ++bs){
      #pragma unroll
      for (int ks=0;ks<2;ks++){
        int bo = (bs*16+l15)*72 + ks*32 + quad*8;
        bf16x8 bhf = *(bf16x8*)&sBh[bo];
        bf16x8 blf = *(bf16x8*)&sBl[bo];
        gacc[bs] = __builtin_amdgcn_mfma_f32_16x16x32_bf16(cah[ks], bhf, gacc[bs], 0,0,0);
        gacc[bs] = __builtin_amdgcn_mfma_f32_16x16x32_bf16(cah[ks], blf, gacc[bs], 0,0,0);
        gacc[bs] = __builtin_amdgcn_mfma_f32_16x16x32_bf16(cal[ks], bhf, gacc[bs], 0,0,0);
      }
    }
  }
  __syncthreads();   // sB reads done -> safe to overwrite with GM

  // ---- scale/mask, write GM single bf16 into sBh; zero needed tiles ----
  for (int bs=0; bs<=w; ++bs){
    #pragma unroll
    for (int r=0;r<4;r++){
      int i = w*16 + quad*4 + r;
      int s = bs*16 + l15;
      float v = 0.f;
      if (s <= i) v = gacc[bs][r] * __expf(sla[i]-sla[s]) * sdt[s];
      sBh[i*72+s] = f2bf(v);
    }
  }
  if (w==0){
    #pragma unroll
    for (int r=0;r<4;r++) sBh[(quad*4+r)*72 + 16+l15] = 0;
  }
  if (w==2){
    #pragma unroll
    for (int r=0;r<4;r++) sBh[(32+quad*4+r)*72 + 48+l15] = 0;
  }
  __syncthreads();

  // ---- Sp fragments direct (single bf16, [p][n] layout) ----
  bf16x8 pah[3][2];
  {
    const ushort_t* sph = Sp + (size_t)blk*3072;
    #pragma unroll
    for (int pt=0;pt<3;pt++)
      #pragma unroll
      for (int ks=0;ks<2;ks++)
        pah[pt][ks] = *(const bf16x8*)(sph + (size_t)(pt*16+l15)*64 + ks*32 + quad*8);
  }

  // ---- O = X^T·GM^T (intra; GM single -> 2 terms) ----
  f32x4 accI[3], accA[3];
  #pragma unroll
  for (int t=0;t<3;t++){ accI[t] = (f32x4)(0.f); accA[t] = (f32x4)(0.f); }
  int nks = (w>=2) ? 2 : 1;
  for (int ks=0; ks<nks; ++ks){
    int go = (w*16+l15)*72 + ks*32 + quad*8;
    bf16x8 gbh = *(bf16x8*)&sBh[go];
    #pragma unroll
    for (int pt=0;pt<3;pt++){
      int xo = (pt*16+l15)*72 + ks*32 + quad*8;
      bf16x8 xah = *(bf16x8*)&sXh[xo];
      bf16x8 xal = *(bf16x8*)&sXl[xo];
      accI[pt] = __builtin_amdgcn_mfma_f32_16x16x32_bf16(xah, gbh, accI[pt], 0,0,0);
      accI[pt] = __builtin_amdgcn_mfma_f32_16x16x32_bf16(xal, gbh, accI[pt], 0,0,0);
    }
  }
  // ---- + Sp^T·C^T (carry; Sp single -> 2 terms) ----
  #pragma unroll
  for (int ks=0; ks<2; ++ks){
    int co = (w*16+l15)*72 + ks*32 + quad*8;
    bf16x8 cbh = *(bf16x8*)&sCh[co];
    bf16x8 cbl = *(bf16x8*)&sCl[co];
    #pragma unroll
    for (int pt=0;pt<3;pt++){
      accA[pt] = __builtin_amdgcn_mfma_f32_16x16x32_bf16(pah[pt][ks], cbh, accA[pt], 0,0,0);
      accA[pt] = __builtin_amdgcn_mfma_f32_16x16x32_bf16(pah[pt][ks], cbl, accA[pt], 0,0,0);
    }
  }
  // ---- epilogue: y = accI + e^la*accA + D*x; g = y*silu(z); ssum += g^2 ----
  {
    int i = w*16 + l15;
    int tok = b*4096 + t0 + i;
    float eli = __expf(sla[i]);
    float Dh = Dparam[hh];
    float4 xv = *(const float4*)(xg + (size_t)tok*4);
    ushort_t* gbase = g16 + (size_t)tok*384 + hh*48;
    float ssq = 0.f;
    #pragma unroll
    for (int pt=0;pt<3;pt++)
      #pragma unroll
      for (int r=0;r<4;r++){
        int p = pt*16 + quad*4 + r;
        float xf = bf2f(sXh[p*72 + i]) + bf2f(sXl[p*72 + i]);
        float yv = accI[pt][r] + eli*accA[pt][r] + Dh*xf;
        int e = hh*48 + p;
        float zv = beff[e];
        zv = fmaf(xv.x, Weff[e], zv);
        zv = fmaf(xv.y, Weff[904+e], zv);
        zv = fmaf(xv.z, Weff[1808+e], zv);
        zv = fmaf(xv.w, Weff[2712+e], zv);
        float gg = yv * (zv * sigmoidf_(zv));
        gbase[p] = f2bf(gg);
        ssq += gg*gg;
      }
    ssq += __shfl_xor(ssq, 16);
    ssq += __shfl_xor(ssq, 32);
    if (quad == 0) atomicAdd(&ssum[tok], ssq);
  }
}

// ----- mlp2: 64 tokens/block, 2 tokens/thread; g bf16 + rms(ssum) inline -----
__global__ __launch_bounds__(256) void k_mlp2(
    const ushort_t* __restrict__ g16, const float* __restrict__ ssum,
    const float* __restrict__ Weff2, const float* __restrict__ b1,
    const float* __restrict__ W2, const float* __restrict__ b2,
    float* __restrict__ macc){
  __shared__ __align__(16) float sW[384][32];
  __shared__ __align__(16) float sm1[64][33];
  __shared__ __align__(16) float sW2[32][32];
  __shared__ __align__(16) float sm2[64][33];
  int tid = threadIdx.x;
  int tok0 = blockIdx.x*64;
  int b = tok0 >> 12;
  #pragma unroll
  for (int r=0;r<12;r++){
    int idx = tid + r*256;
    int row = idx>>3, c4 = (idx&7)*4;
    *(float4*)&sW[row][c4] = *(const float4*)(Weff2 + (size_t)idx*4);
  }
  {
    int row = tid>>3, c4 = (tid&7)*4;
    *(float4*)&sW2[row][c4] = *(const float4*)(W2 + row*32 + c4);
  }
  __syncthreads();
  {
    int tk = tid>>3, j0 = (tid&7)*4;
    float rms0 = rsqrtf(ssum[tok0+tk]*(1.f/384.f) + 1e-5f);
    float rms1 = rsqrtf(ssum[tok0+tk+32]*(1.f/384.f) + 1e-5f);
    float a0[4], a1[4];
    #pragma unroll
    for (int j=0;j<4;j++){ a0[j] = b1[j0+j]; a1[j] = a0[j]; }
    const ushort_t* y0 = g16 + (size_t)(tok0+tk)*384;
    const ushort_t* y1 = g16 + (size_t)(tok0+tk+32)*384;
    for (int k8=0;k8<48;k8++){
      ushort_t ua[8], ub[8];
      *(uint4*)ua = *(const uint4*)(y0 + k8*8);
      *(uint4*)ub = *(const uint4*)(y1 + k8*8);
      #pragma unroll
      for (int c=0;c<8;c++){
        float va = bf2f(ua[c])*rms0, vb = bf2f(ub[c])*rms1;
        float w[4]; *(float4*)w = *(float4*)&sW[k8*8+c][j0];
        #pragma unroll
        for (int j=0;j<4;j++){ a0[j] = fmaf(va, w[j], a0[j]); a1[j] = fmaf(vb, w[j], a1[j]); }
      }
    }
    #pragma unroll
    for (int j=0;j<4;j++){
      sm1[tk][j0+j]    = fmaxf(a0[j], 0.f);
      sm1[tk+32][j0+j] = fmaxf(a1[j], 0.f);
    }
  }
  __syncthreads();
  {
    int tk = tid>>3, j0 = (tid&7)*4;
    float a0[4], a1[4];
    #pragma unroll
    for (int j=0;j<4;j++){ a0[j] = b2[j0+j]; a1[j] = a0[j]; }
    #pragma unroll
    for (int kk=0;kk<32;kk++){
      float va = sm1[tk][kk];
      float vb = sm1[tk+32][kk];
      float w[4]; *(float4*)w = *(float4*)&sW2[kk][j0];
      #pragma unroll
      for (int j=0;j<4;j++){ a0[j] = fmaf(va, w[j], a0[j]); a1[j] = fmaf(vb, w[j], a1[j]); }
    }
    #pragma unroll
    for (int j=0;j<4;j++){
      sm2[tk][j0+j]    = fmaxf(a0[j], 0.f);
      sm2[tk+32][j0+j] = fmaxf(a1[j], 0.f);
    }
  }
  __syncthreads();
  if (tid < 32){
    float t = 0.f;
    #pragma unroll
    for (int tok=0;tok<64;tok++) t += sm2[tok][tid];
    atomicAdd(&macc[b*32 + tid], t);
  }
}

// ----- final: angle[b] = mean_m @ Wo + bo -----
__global__ void k_final(const float* __restrict__ macc, const float* __restrict__ Wo,
                        const float* __restrict__ bo, float* __restrict__ out){
  int tid = threadIdx.x;
  if (tid < 4){
    float acc = bo[0];
    #pragma unroll
    for (int j=0;j<32;j++) acc = fmaf(macc[tid*32+j]*(1.f/4096.f), Wo[j], acc);
    out[tid] = acc;
  }
}

// ---------------------------------------------------------------------------
extern "C" void kernel_launch(void* const* d_in, const int* in_sizes, int n_in,
                              void* d_out, int out_size, void* d_ws, size_t ws_size,
                              hipStream_t stream){
  const float* x      = (const float*)d_in[0];
  const float* Wfc    = (const float*)d_in[1];
  const float* bfc    = (const float*)d_in[2];
  const float* W_in   = (const float*)d_in[3];
  const float* conv_w = (const float*)d_in[4];
  const float* conv_b = (const float*)d_in[5];
  const float* dt_bias= (const float*)d_in[6];
  const float* A_log  = (const float*)d_in[7];
  const float* Dparam = (const float*)d_in[8];
  const float* norm_w = (const float*)d_in[9];
  const float* W_out  = (const float*)d_in[10];
  const float* W1     = (const float*)d_in[11];
  const float* b1     = (const float*)d_in[12];
  const float* W2     = (const float*)d_in[13];
  const float* b2     = (const float*)d_in[14];
  const float* Wo     = (const float*)d_in[15];
  const float* bo     = (const float*)d_in[16];
  float* ws  = (float*)d_ws;
  float* out = (float*)d_out;

  float* Weff  = ws + OFF_W;
  float* beff  = ws + OFF_W + 4096;
  float* Weff2 = ws + OFF_W + 8192;
  float* ssum  = ws + OFF_Z;            // 16384 fp32
  ushort_t* Tb   = (ushort_t*)(ws + OFF_T);
  ushort_t* xs_h = (ushort_t*)(ws + OFF_XS);
  ushort_t* xs_l = xs_h + 6291456u;     // 32*4096*48
  ushort_t* Bm_h = (ushort_t*)(ws + OFF_BM);
  ushort_t* Bm_l = Bm_h + 1048576u;     // 16384*64
  ushort_t* Cm_h = (ushort_t*)(ws + OFF_CM);
  ushort_t* Cm_l = Cm_h + 1048576u;
  float* dtb   = ws + OFF_DT;
  float* lacb  = ws + OFF_LAC;
  ushort_t* Spb  = (ushort_t*)(ws + OFF_SP);
  ushort_t* g16 = (ushort_t*)(ws + OFF_Y);
  float* macc  = ws + OFF_MACC;

  k_prep<<<dim3(116), dim3(256), 0, stream>>>(Wfc, bfc, W_in, W_out, W1, norm_w,
                                              Weff, beff, Weff2, macc, ssum);
  k_ipc<<<dim3(BL/4), dim3(256), 0, stream>>>(x, Weff, beff, conv_w, conv_b,
                                              dt_bias, xs_h, xs_l, Bm_h, Bm_l,
                                              Cm_h, Cm_l, dtb);
  k_phase1<<<dim3(BH*NC), dim3(256), 0, stream>>>(dtb, Bm_h, Bm_l, xs_h, xs_l,
                                                  A_log, Tb, lacb);
  k_phase2p<<<dim3(BH,48), dim3(256), 0, stream>>>(Tb, lacb, Spb);
  k_phase3<<<dim3(BH*NC), dim3(256), 0, stream>>>(dtb, lacb, Bm_h, Bm_l,
                                                  Cm_h, Cm_l, xs_h, xs_l,
                                                  Spb, Dparam, x, Weff, beff,
                                                  g16, ssum);
  k_mlp2<<<dim3(BL/64), dim3(256), 0, stream>>>(g16, ssum, Weff2, b1, W2, b2, macc);
  k_final<<<dim3(1), dim3(64), 0, stream>>>(macc, Wo, bo, out);
}